// Round 1
// baseline (2059.960 us; speedup 1.0000x reference)
//
#include <hip/hip_runtime.h>
#include <math.h>

#define HH 8
#define C2 128
#define NEG 0.2f

static const int N_S = 10000, N_D = 2000, E_N = 100000, L_N = 50000;

// ---------- helpers ----------
__device__ inline unsigned f2mono(float f) {
  unsigned b = __float_as_uint(f);
  return (b & 0x80000000u) ? ~b : (b | 0x80000000u);
}
__device__ inline float mono2f(unsigned u) {
  return (u & 0x80000000u) ? __uint_as_float(u & 0x7fffffffu) : __uint_as_float(~u);
}

// ---------- edge scatter-sum: out[ed[e]] += src[es[e]]  (C = 2^lc) ----------
__global__ void k_edge_segsum(const float* __restrict__ src, const int* __restrict__ es,
                              const int* __restrict__ ed, float* __restrict__ out,
                              int E, int lc) {
  long long i = (long long)blockIdx.x * blockDim.x + threadIdx.x;
  long long total = (long long)E << lc;
  if (i >= total) return;
  int e = (int)(i >> lc);
  int c = (int)(i & ((1 << lc) - 1));
  atomicAdd(&out[((long long)ed[e] << lc) + c], src[((long long)es[e] << lc) + c]);
}

// ---------- fused dense: out = [relu]( A@W1 + [B@W2] + bias ) ----------
template<int RELU, int HASB>
__global__ void k_dense2(const float* __restrict__ A, const float* __restrict__ W1, int K1,
                         const float* __restrict__ B, const float* __restrict__ W2, int K2,
                         const float* __restrict__ bias, float* __restrict__ out,
                         int N, int M) {
  int m = blockIdx.x * 64 + threadIdx.x;
  int n = blockIdx.y * blockDim.y + threadIdx.y;
  if (n >= N || m >= M) return;
  float acc = bias[m];
  const float* a = A + (long long)n * K1;
  #pragma unroll 8
  for (int k = 0; k < K1; ++k) acc = fmaf(a[k], W1[k * M + m], acc);
  if (HASB) {
    const float* b = B + (long long)n * K2;
    #pragma unroll 8
    for (int k = 0; k < K2; ++k) acc = fmaf(b[k], W2[k * M + m], acc);
  }
  if (RELU) acc = fmaxf(acc, 0.f);
  out[(long long)n * M + m] = acc;
}

// ---------- GATv2 score: one wave per (edge, head) ----------
__global__ void k_gat_score(const float* __restrict__ xl, const float* __restrict__ xr,
                            const int* __restrict__ es, const int* __restrict__ ed,
                            const float* __restrict__ att, float* __restrict__ score, int E) {
  long long t = (long long)blockIdx.x * blockDim.x + threadIdx.x;
  int gw = (int)(t >> 6);
  int lane = (int)(t & 63);
  if (gw >= E * HH) return;
  int e = gw >> 3, h = gw & 7;
  long long s = es[e], d = ed[e];
  const float* pl = xl + s * 1024 + h * C2;
  const float* pr = xr + d * 1024 + h * C2;
  const float* pa = att + h * C2;
  float v = 0.f;
  #pragma unroll
  for (int i = 0; i < 2; ++i) {
    int c = lane + (i << 6);
    float x = pl[c] + pr[c];
    x = (x > 0.f) ? x : NEG * x;
    v = fmaf(x, pa[c], v);
  }
  #pragma unroll
  for (int off = 32; off; off >>= 1) v += __shfl_down(v, off);
  if (lane == 0) score[gw] = v;
}

// ---------- segment max via monotone-uint atomicMax ----------
__global__ void k_seg_max(const float* __restrict__ score, const int* __restrict__ ed,
                          unsigned* __restrict__ m, int E) {
  int i = blockIdx.x * blockDim.x + threadIdx.x;
  if (i >= E * HH) return;
  int e = i >> 3, h = i & 7;
  atomicMax(&m[(long long)ed[e] * HH + h], f2mono(score[i]));
}

// ---------- exp + denom + weighted aggregation (unnormalized) ----------
__global__ void k_gat_agg(const float* __restrict__ xl, const float* __restrict__ score,
                          const unsigned* __restrict__ m,
                          const int* __restrict__ es, const int* __restrict__ ed,
                          float* __restrict__ acc, float* __restrict__ den, int E) {
  long long t = (long long)blockIdx.x * blockDim.x + threadIdx.x;
  int gw = (int)(t >> 6), lane = (int)(t & 63);
  if (gw >= E * HH) return;
  int e = gw >> 3, h = gw & 7;
  long long s = es[e], d = ed[e];
  float a = __expf(score[gw] - mono2f(m[d * HH + h]));
  if (lane == 0) atomicAdd(&den[d * HH + h], a);
  const float* pl = xl + s * 1024 + h * C2;
  float* pd = acc + d * 1024 + h * C2;
  #pragma unroll
  for (int i = 0; i < 2; ++i) {
    int c = lane + (i << 6);
    atomicAdd(&pd[c], a * pl[c]);
  }
}

// ---------- finalize: divide by denom, mean heads, +bias, relu ----------
__global__ void k_gat_fin(const float* __restrict__ acc, const float* __restrict__ den,
                          const float* __restrict__ bias, float* __restrict__ out, int N) {
  int i = blockIdx.x * blockDim.x + threadIdx.x;
  if (i >= N * C2) return;
  int n = i >> 7, c = i & 127;
  float v = 0.f;
  #pragma unroll
  for (int h = 0; h < HH; ++h) {
    float dd = den[n * HH + h];
    if (dd > 0.f) v += acc[(long long)n * 1024 + h * C2 + c] / dd;
  }
  v = v * (1.f / HH) + bias[c];
  out[i] = fmaxf(v, 0.f);
}

// ---------- classifier: per label-edge 64-dim dot ----------
__global__ void k_dot64(const float* __restrict__ xs, const float* __restrict__ xd,
                        const int* __restrict__ ls, const int* __restrict__ ld,
                        float* __restrict__ out, int L) {
  long long t = (long long)blockIdx.x * blockDim.x + threadIdx.x;
  int gw = (int)(t >> 6), lane = (int)(t & 63);
  if (gw >= L) return;
  float v = xs[(long long)ls[gw] * 64 + lane] * xd[(long long)ld[gw] * 64 + lane];
  #pragma unroll
  for (int off = 32; off; off >>= 1) v += __shfl_down(v, off);
  if (lane == 0) out[gw] = v;
}

extern "C" void kernel_launch(void* const* d_in, const int* in_sizes, int n_in,
                              void* d_out, int out_size, void* d_ws, size_t ws_size,
                              hipStream_t stream) {
  const float* x_s = (const float*)d_in[0];
  const float* x_d = (const float*)d_in[1];
  const int* esrc = (const int*)d_in[2];
  const int* edst = (const int*)d_in[3];
  const int* lsrc = (const int*)d_in[4];
  const int* ldst = (const int*)d_in[5];
  const float* W1rel_sd  = (const float*)d_in[6];
  const float* b1_sd     = (const float*)d_in[7];
  const float* W1root_sd = (const float*)d_in[8];
  const float* W1rel_ds  = (const float*)d_in[9];
  const float* b1_ds     = (const float*)d_in[10];
  const float* W1root_ds = (const float*)d_in[11];
  const float *Wl2_sd = (const float*)d_in[12], *bl2_sd = (const float*)d_in[13],
              *Wr2_sd = (const float*)d_in[14], *br2_sd = (const float*)d_in[15],
              *att2_sd = (const float*)d_in[16], *bias2_sd = (const float*)d_in[17];
  const float *Wl2_ds = (const float*)d_in[18], *bl2_ds = (const float*)d_in[19],
              *Wr2_ds = (const float*)d_in[20], *br2_ds = (const float*)d_in[21],
              *att2_ds = (const float*)d_in[22], *bias2_ds = (const float*)d_in[23];
  const float *W3rel_sd = (const float*)d_in[24], *b3_sd = (const float*)d_in[25],
              *W3root_sd = (const float*)d_in[26];
  const float *W3rel_ds = (const float*)d_in[27], *b3_ds = (const float*)d_in[28],
              *W3root_ds = (const float*)d_in[29];
  float* out = (float*)d_out;

  // ---- workspace arena (floats), 256B-aligned carve ----
  float* w = (float*)d_ws;
  long long off = 0;
  auto alloc = [&](long long n) { float* p = w + off; off += (n + 63) & ~63LL; return p; };
  float* XS1   = alloc((long long)N_S * 128);
  float* XD1   = alloc((long long)N_D * 128);
  float* XS2   = alloc((long long)N_S * 128);
  float* XD2   = alloc((long long)N_D * 128);
  float* XS3   = alloc((long long)N_S * 64);
  float* XD3   = alloc((long long)N_D * 64);
  float* AGG_S = alloc((long long)N_S * 128);
  float* AGG_D = alloc((long long)N_D * 128);
  float* SCORE = alloc((long long)E_N * HH);
  float* MB    = alloc((long long)N_S * HH);
  float* DEN   = alloc((long long)N_S * HH);
  float* BIG   = alloc(22528000LL);   // union arena for per-direction GAT temps
  (void)ws_size; (void)in_sizes; (void)n_in; (void)out_size;

  // ================= layer 1: GraphConv both directions =================
  hipMemsetAsync(AGG_D, 0, (size_t)N_D * 128 * 4, stream);
  hipMemsetAsync(AGG_S, 0, (size_t)N_S * 64 * 4, stream);
  {
    long long tot = (long long)E_N * 128;
    k_edge_segsum<<<(int)((tot + 255) / 256), 256, 0, stream>>>(x_s, esrc, edst, AGG_D, E_N, 7);
    tot = (long long)E_N * 64;
    k_edge_segsum<<<(int)((tot + 255) / 256), 256, 0, stream>>>(x_d, edst, esrc, AGG_S, E_N, 6);
  }
  k_dense2<1, 1><<<dim3(2, (N_D + 3) / 4), dim3(64, 4), 0, stream>>>(
      AGG_D, W1rel_sd, 128, x_d, W1root_sd, 64, b1_sd, XD1, N_D, 128);
  k_dense2<1, 1><<<dim3(2, (N_S + 3) / 4), dim3(64, 4), 0, stream>>>(
      AGG_S, W1rel_ds, 64, x_s, W1root_ds, 128, b1_ds, XS1, N_S, 128);

  // ================= layer 2: GATv2 both directions =================
  auto gat = [&](const float* xsrc, int Nsrc, const float* xdst, int Ndst,
                 const int* es, const int* ed,
                 const float* Wl, const float* bl, const float* Wr, const float* br,
                 const float* att, const float* bias, float* outv) {
    float* XL  = BIG;
    float* XR  = BIG + (long long)Nsrc * 1024;
    float* ACC = XR + (long long)Ndst * 1024;
    k_dense2<0, 0><<<dim3(16, (Nsrc + 3) / 4), dim3(64, 4), 0, stream>>>(
        xsrc, Wl, 128, nullptr, nullptr, 0, bl, XL, Nsrc, 1024);
    k_dense2<0, 0><<<dim3(16, (Ndst + 3) / 4), dim3(64, 4), 0, stream>>>(
        xdst, Wr, 128, nullptr, nullptr, 0, br, XR, Ndst, 1024);
    long long tw = (long long)E_N * HH * 64;
    k_gat_score<<<(int)((tw + 255) / 256), 256, 0, stream>>>(XL, XR, es, ed, att, SCORE, E_N);
    hipMemsetAsync(MB, 0, (size_t)Ndst * HH * 4, stream);
    k_seg_max<<<(E_N * HH + 255) / 256, 256, 0, stream>>>(SCORE, ed, (unsigned*)MB, E_N);
    hipMemsetAsync(DEN, 0, (size_t)Ndst * HH * 4, stream);
    hipMemsetAsync(ACC, 0, (size_t)Ndst * 1024 * 4, stream);
    k_gat_agg<<<(int)((tw + 255) / 256), 256, 0, stream>>>(
        XL, SCORE, (const unsigned*)MB, es, ed, ACC, DEN, E_N);
    k_gat_fin<<<(Ndst * 128 + 255) / 256, 256, 0, stream>>>(ACC, DEN, bias, outv, Ndst);
  };
  gat(XS1, N_S, XD1, N_D, esrc, edst, Wl2_sd, bl2_sd, Wr2_sd, br2_sd, att2_sd, bias2_sd, XD2);
  gat(XD1, N_D, XS1, N_S, edst, esrc, Wl2_ds, bl2_ds, Wr2_ds, br2_ds, att2_ds, bias2_ds, XS2);

  // ================= layer 3: GraphConv both directions =================
  hipMemsetAsync(AGG_D, 0, (size_t)N_D * 128 * 4, stream);
  hipMemsetAsync(AGG_S, 0, (size_t)N_S * 128 * 4, stream);
  {
    long long tot = (long long)E_N * 128;
    k_edge_segsum<<<(int)((tot + 255) / 256), 256, 0, stream>>>(XS2, esrc, edst, AGG_D, E_N, 7);
    k_edge_segsum<<<(int)((tot + 255) / 256), 256, 0, stream>>>(XD2, edst, esrc, AGG_S, E_N, 7);
  }
  k_dense2<0, 1><<<dim3(1, (N_D + 3) / 4), dim3(64, 4), 0, stream>>>(
      AGG_D, W3rel_sd, 128, XD2, W3root_sd, 128, b3_sd, XD3, N_D, 64);
  k_dense2<0, 1><<<dim3(1, (N_S + 3) / 4), dim3(64, 4), 0, stream>>>(
      AGG_S, W3rel_ds, 128, XS2, W3root_ds, 128, b3_ds, XS3, N_S, 64);

  // ================= classifier =================
  long long tw = (long long)L_N * 64;
  k_dot64<<<(int)((tw + 255) / 256), 256, 0, stream>>>(XS3, XD3, lsrc, ldst, out, L_N);
}

// Round 2
// 1104.843 us; speedup vs baseline: 1.8645x; 1.8645x over previous
//
#include <hip/hip_runtime.h>
#include <math.h>

#define HH 8
#define C2 128
#define NEG 0.2f

static const int N_S = 10000, N_D = 2000, E_N = 100000, L_N = 50000;

// ================= CSR build =================
__global__ void k_hist(const int* __restrict__ key, int* __restrict__ deg, int E) {
  int e = blockIdx.x * 256 + threadIdx.x;
  if (e < E) atomicAdd(&deg[key[e]], 1);
}

// single-block Hillis-Steele scan over chunks of 1024
__global__ void k_scan(const int* __restrict__ deg, int* __restrict__ rowptr, int N) {
  __shared__ int buf[1024];
  __shared__ int carry;
  if (threadIdx.x == 0) carry = 0;
  __syncthreads();
  for (int base = 0; base < N; base += 1024) {
    int i = base + threadIdx.x;
    int v = (i < N) ? deg[i] : 0;
    buf[threadIdx.x] = v;
    __syncthreads();
    for (int st = 1; st < 1024; st <<= 1) {
      int t = (threadIdx.x >= st) ? buf[threadIdx.x - st] : 0;
      __syncthreads();
      buf[threadIdx.x] += t;
      __syncthreads();
    }
    int incl = buf[threadIdx.x];
    if (i < N) rowptr[i] = carry + incl - v;     // exclusive
    int total = buf[1023];
    __syncthreads();
    if (threadIdx.x == 0) {
      if (base + 1024 >= N) rowptr[N] = carry + total;
      carry += total;
    }
    __syncthreads();
  }
}

__global__ void k_csr_scatter(const int* __restrict__ key, const int* __restrict__ val,
                              int* __restrict__ cursor, int* __restrict__ csrc, int E) {
  int e = blockIdx.x * 256 + threadIdx.x;
  if (e >= E) return;
  int pos = atomicAdd(&cursor[key[e]], 1);
  csrc[pos] = val[e];
}

// ================= CSR gather-sum (GraphConv aggregation) =================
template<int C>
__global__ void k_csr_gather_sum(const float* __restrict__ x, const int* __restrict__ rowptr,
                                 const int* __restrict__ src, float* __restrict__ out) {
  int n = blockIdx.x;
  int c = threadIdx.x;
  int b = rowptr[n], e = rowptr[n + 1];
  float acc = 0.f;
  int i = b;
  for (; i + 1 < e; i += 2) {
    float v0 = x[(long long)src[i] * C + c];
    float v1 = x[(long long)src[i + 1] * C + c];
    acc += v0 + v1;
  }
  if (i < e) acc += x[(long long)src[i] * C + c];
  out[(long long)n * C + c] = acc;
}

// ================= fused dense: out = [relu]( A@W1 + [B@W2] + bias ) =================
template<int RELU, int HASB>
__global__ void k_dense2(const float* __restrict__ A, const float* __restrict__ W1, int K1,
                         const float* __restrict__ B, const float* __restrict__ W2, int K2,
                         const float* __restrict__ bias, float* __restrict__ out,
                         int N, int M) {
  int m = blockIdx.x * 64 + threadIdx.x;
  int n = blockIdx.y * blockDim.y + threadIdx.y;
  if (n >= N || m >= M) return;
  float acc = bias[m];
  const float* a = A + (long long)n * K1;
  #pragma unroll 8
  for (int k = 0; k < K1; ++k) acc = fmaf(a[k], W1[k * M + m], acc);
  if (HASB) {
    const float* b = B + (long long)n * K2;
    #pragma unroll 8
    for (int k = 0; k < K2; ++k) acc = fmaf(b[k], W2[k * M + m], acc);
  }
  if (RELU) acc = fmaxf(acc, 0.f);
  out[(long long)n * M + m] = acc;
}

// ================= fused GATv2: score+softmax+aggregate+mean+bias+relu =================
// one block per dst node; wave h handles head h; online softmax over in-edges
__global__ __launch_bounds__(512) void k_gatv2_fused(
    const float* __restrict__ xl,   // [Nsrc, 8, 128]
    const float* __restrict__ xr,   // [Ndst, 8, 128]
    const int* __restrict__ rowptr, const int* __restrict__ srcid,
    const float* __restrict__ att,  // [8,128]
    const float* __restrict__ bias, // [128]
    float* __restrict__ out) {      // [Ndst,128]
  int d = blockIdx.x;
  int h = threadIdx.x >> 6;
  int lane = threadIdx.x & 63;
  __shared__ float red[8][128];

  const float* pr = xr + (long long)d * 1024 + h * C2;
  float xr0 = pr[lane], xr1 = pr[lane + 64];
  float a0 = att[h * C2 + lane], a1 = att[h * C2 + lane + 64];

  float m = -INFINITY, s = 0.f, acc0 = 0.f, acc1 = 0.f;
  int b = rowptr[d], e = rowptr[d + 1];
  for (int i = b; i < e; ++i) {
    const float* pl = xl + (long long)srcid[i] * 1024 + h * C2;
    float x0 = pl[lane], x1 = pl[lane + 64];
    float t0 = x0 + xr0; t0 = (t0 > 0.f) ? t0 : NEG * t0;
    float t1 = x1 + xr1; t1 = (t1 > 0.f) ? t1 : NEG * t1;
    float v = fmaf(t0, a0, t1 * a1);
    #pragma unroll
    for (int o = 32; o; o >>= 1) v += __shfl_xor(v, o);
    if (v > m) {                       // rescale old state
      float sc = __expf(m - v);        // exp(-inf)=0 handles first edge
      s *= sc; acc0 *= sc; acc1 *= sc; m = v;
    }
    float a = __expf(v - m);
    s += a;
    acc0 = fmaf(a, x0, acc0);
    acc1 = fmaf(a, x1, acc1);
  }
  float inv = (s > 0.f) ? 1.f / s : 0.f;
  red[h][lane] = acc0 * inv;
  red[h][lane + 64] = acc1 * inv;
  __syncthreads();
  if (threadIdx.x < C2) {
    int c = threadIdx.x;
    float v = 0.f;
    #pragma unroll
    for (int hh = 0; hh < HH; ++hh) v += red[hh][c];
    v = v * 0.125f + bias[c];
    out[(long long)d * C2 + c] = fmaxf(v, 0.f);
  }
}

// ================= classifier =================
__global__ void k_dot64(const float* __restrict__ xs, const float* __restrict__ xd,
                        const int* __restrict__ ls, const int* __restrict__ ld,
                        float* __restrict__ out, int L) {
  long long t = (long long)blockIdx.x * blockDim.x + threadIdx.x;
  int gw = (int)(t >> 6), lane = (int)(t & 63);
  if (gw >= L) return;
  float v = xs[(long long)ls[gw] * 64 + lane] * xd[(long long)ld[gw] * 64 + lane];
  #pragma unroll
  for (int off = 32; off; off >>= 1) v += __shfl_down(v, off);
  if (lane == 0) out[gw] = v;
}

extern "C" void kernel_launch(void* const* d_in, const int* in_sizes, int n_in,
                              void* d_out, int out_size, void* d_ws, size_t ws_size,
                              hipStream_t stream) {
  const float* x_s = (const float*)d_in[0];
  const float* x_d = (const float*)d_in[1];
  const int* esrc = (const int*)d_in[2];
  const int* edst = (const int*)d_in[3];
  const int* lsrc = (const int*)d_in[4];
  const int* ldst = (const int*)d_in[5];
  const float* W1rel_sd  = (const float*)d_in[6];
  const float* b1_sd     = (const float*)d_in[7];
  const float* W1root_sd = (const float*)d_in[8];
  const float* W1rel_ds  = (const float*)d_in[9];
  const float* b1_ds     = (const float*)d_in[10];
  const float* W1root_ds = (const float*)d_in[11];
  const float *Wl2_sd = (const float*)d_in[12], *bl2_sd = (const float*)d_in[13],
              *Wr2_sd = (const float*)d_in[14], *br2_sd = (const float*)d_in[15],
              *att2_sd = (const float*)d_in[16], *bias2_sd = (const float*)d_in[17];
  const float *Wl2_ds = (const float*)d_in[18], *bl2_ds = (const float*)d_in[19],
              *Wr2_ds = (const float*)d_in[20], *br2_ds = (const float*)d_in[21],
              *att2_ds = (const float*)d_in[22], *bias2_ds = (const float*)d_in[23];
  const float *W3rel_sd = (const float*)d_in[24], *b3_sd = (const float*)d_in[25],
              *W3root_sd = (const float*)d_in[26];
  const float *W3rel_ds = (const float*)d_in[27], *b3_ds = (const float*)d_in[28],
              *W3root_ds = (const float*)d_in[29];
  float* out = (float*)d_out;

  // ---- workspace arena ----
  float* w = (float*)d_ws;
  long long off = 0;
  auto alloc = [&](long long n) { float* p = w + off; off += (n + 63) & ~63LL; return p; };
  float* XS1   = alloc((long long)N_S * 128);
  float* XD1   = alloc((long long)N_D * 128);
  float* XS2   = alloc((long long)N_S * 128);
  float* XD2   = alloc((long long)N_D * 128);
  float* XS3   = alloc((long long)N_S * 64);
  float* XD3   = alloc((long long)N_D * 64);
  float* AGG_S = alloc((long long)N_S * 128);
  float* AGG_D = alloc((long long)N_D * 128);
  // CSR (int) area
  int* rowptr_d = (int*)alloc(N_D + 64);
  int* rowptr_s = (int*)alloc(N_S + 64);
  int* cur_d    = (int*)alloc(N_D + 64);
  int* cur_s    = (int*)alloc(N_S + 64);
  int* csrc_d   = (int*)alloc(E_N);      // src ids of edges into disease
  int* csrc_s   = (int*)alloc(E_N);      // src ids of edges into snorna
  float* BIG    = alloc(22528000LL);     // XL/XR arena for GAT
  (void)ws_size; (void)in_sizes; (void)n_in; (void)out_size;

  // ================= build CSR both directions (graph reused by layers 1,2,3) ====
  hipMemsetAsync(cur_d, 0, (size_t)N_D * 4, stream);
  hipMemsetAsync(cur_s, 0, (size_t)N_S * 4, stream);
  k_hist<<<(E_N + 255) / 256, 256, 0, stream>>>(edst, cur_d, E_N);
  k_hist<<<(E_N + 255) / 256, 256, 0, stream>>>(esrc, cur_s, E_N);
  k_scan<<<1, 1024, 0, stream>>>(cur_d, rowptr_d, N_D);
  k_scan<<<1, 1024, 0, stream>>>(cur_s, rowptr_s, N_S);
  hipMemcpyAsync(cur_d, rowptr_d, (size_t)N_D * 4, hipMemcpyDeviceToDevice, stream);
  hipMemcpyAsync(cur_s, rowptr_s, (size_t)N_S * 4, hipMemcpyDeviceToDevice, stream);
  k_csr_scatter<<<(E_N + 255) / 256, 256, 0, stream>>>(edst, esrc, cur_d, csrc_d, E_N);
  k_csr_scatter<<<(E_N + 255) / 256, 256, 0, stream>>>(esrc, edst, cur_s, csrc_s, E_N);

  // ================= layer 1: GraphConv =================
  k_csr_gather_sum<128><<<N_D, 128, 0, stream>>>(x_s, rowptr_d, csrc_d, AGG_D);
  k_csr_gather_sum<64><<<N_S, 64, 0, stream>>>(x_d, rowptr_s, csrc_s, AGG_S);
  k_dense2<1, 1><<<dim3(2, (N_D + 3) / 4), dim3(64, 4), 0, stream>>>(
      AGG_D, W1rel_sd, 128, x_d, W1root_sd, 64, b1_sd, XD1, N_D, 128);
  k_dense2<1, 1><<<dim3(2, (N_S + 3) / 4), dim3(64, 4), 0, stream>>>(
      AGG_S, W1rel_ds, 64, x_s, W1root_ds, 128, b1_ds, XS1, N_S, 128);

  // ================= layer 2: GATv2 =================
  auto gat = [&](const float* xsrc, int Nsrc, const float* xdst, int Ndst,
                 const int* rowptr, const int* srcid,
                 const float* Wl, const float* bl, const float* Wr, const float* br,
                 const float* att, const float* bias, float* outv) {
    float* XL = BIG;
    float* XR = BIG + (long long)Nsrc * 1024;
    k_dense2<0, 0><<<dim3(16, (Nsrc + 3) / 4), dim3(64, 4), 0, stream>>>(
        xsrc, Wl, 128, nullptr, nullptr, 0, bl, XL, Nsrc, 1024);
    k_dense2<0, 0><<<dim3(16, (Ndst + 3) / 4), dim3(64, 4), 0, stream>>>(
        xdst, Wr, 128, nullptr, nullptr, 0, br, XR, Ndst, 1024);
    k_gatv2_fused<<<Ndst, 512, 0, stream>>>(XL, XR, rowptr, srcid, att, bias, outv);
  };
  gat(XS1, N_S, XD1, N_D, rowptr_d, csrc_d,
      Wl2_sd, bl2_sd, Wr2_sd, br2_sd, att2_sd, bias2_sd, XD2);
  gat(XD1, N_D, XS1, N_S, rowptr_s, csrc_s,
      Wl2_ds, bl2_ds, Wr2_ds, br2_ds, att2_ds, bias2_ds, XS2);

  // ================= layer 3: GraphConv =================
  k_csr_gather_sum<128><<<N_D, 128, 0, stream>>>(XS2, rowptr_d, csrc_d, AGG_D);
  k_csr_gather_sum<128><<<N_S, 128, 0, stream>>>(XD2, rowptr_s, csrc_s, AGG_S);
  k_dense2<0, 1><<<dim3(1, (N_D + 3) / 4), dim3(64, 4), 0, stream>>>(
      AGG_D, W3rel_sd, 128, XD2, W3root_sd, 128, b3_sd, XD3, N_D, 64);
  k_dense2<0, 1><<<dim3(1, (N_S + 3) / 4), dim3(64, 4), 0, stream>>>(
      AGG_S, W3rel_ds, 128, XS2, W3root_ds, 128, b3_ds, XS3, N_S, 64);

  // ================= classifier =================
  long long tw = (long long)L_N * 64;
  k_dot64<<<(int)((tw + 255) / 256), 256, 0, stream>>>(XS3, XD3, lsrc, ldst, out, L_N);
}

// Round 3
// 444.685 us; speedup vs baseline: 4.6324x; 2.4846x over previous
//
#include <hip/hip_runtime.h>
#include <math.h>

#define HH 8
#define C2 128
#define NEG 0.2f

static const int N_S = 10000, N_D = 2000, E_N = 100000, L_N = 50000;

// ================= CSR build =================
__global__ void k_hist(const int* __restrict__ key, int* __restrict__ deg, int E) {
  int e = blockIdx.x * 256 + threadIdx.x;
  if (e < E) atomicAdd(&deg[key[e]], 1);
}

// single-block Hillis-Steele scan over chunks of 1024
__global__ void k_scan(const int* __restrict__ deg, int* __restrict__ rowptr, int N) {
  __shared__ int buf[1024];
  __shared__ int carry;
  if (threadIdx.x == 0) carry = 0;
  __syncthreads();
  for (int base = 0; base < N; base += 1024) {
    int i = base + threadIdx.x;
    int v = (i < N) ? deg[i] : 0;
    buf[threadIdx.x] = v;
    __syncthreads();
    for (int st = 1; st < 1024; st <<= 1) {
      int t = (threadIdx.x >= st) ? buf[threadIdx.x - st] : 0;
      __syncthreads();
      buf[threadIdx.x] += t;
      __syncthreads();
    }
    int incl = buf[threadIdx.x];
    if (i < N) rowptr[i] = carry + incl - v;     // exclusive
    int total = buf[1023];
    __syncthreads();
    if (threadIdx.x == 0) {
      if (base + 1024 >= N) rowptr[N] = carry + total;
      carry += total;
    }
    __syncthreads();
  }
}

__global__ void k_csr_scatter(const int* __restrict__ key, const int* __restrict__ val,
                              int* __restrict__ cursor, int* __restrict__ csrc, int E) {
  int e = blockIdx.x * 256 + threadIdx.x;
  if (e >= E) return;
  int pos = atomicAdd(&cursor[key[e]], 1);
  csrc[pos] = val[e];
}

// ================= CSR gather-sum (GraphConv aggregation) =================
template<int C>
__global__ void k_csr_gather_sum(const float* __restrict__ x, const int* __restrict__ rowptr,
                                 const int* __restrict__ src, float* __restrict__ out) {
  int n = blockIdx.x;
  int c = threadIdx.x;
  int b = rowptr[n], e = rowptr[n + 1];
  float acc = 0.f;
  int i = b;
  for (; i + 1 < e; i += 2) {
    float v0 = x[(long long)src[i] * C + c];
    float v1 = x[(long long)src[i + 1] * C + c];
    acc += v0 + v1;
  }
  if (i < e) acc += x[(long long)src[i] * C + c];
  out[(long long)n * C + c] = acc;
}

// ================= tiled fp32 GEMM: out = [relu]( sum_p A_p@W_p + bias ) ==========
// 64x64 tile, BK=32, 256 threads, 4x4 micro-tile per thread.
// A_p: [N,K_p] row-major; W_p: [K_p,M] row-major; K_p % 32 == 0; M % 64 == 0 or M==64.
template<int RELU, int NPAIR>
__global__ __launch_bounds__(256) void k_gemm(
    const float* __restrict__ A0, const float* __restrict__ W0, int K0,
    const float* __restrict__ A1, const float* __restrict__ W1, int K1,
    const float* __restrict__ bias, float* __restrict__ out, int N, int M) {
  __shared__ float AsT[32][68];   // A tile transposed: AsT[k][row]
  __shared__ float Bs[32][68];    // B tile: Bs[k][m]
  int tx = threadIdx.x & 15, ty = threadIdx.x >> 4;
  int m0 = blockIdx.x * 64, n0 = blockIdx.y * 64;
  float acc[4][4] = {};
  const float* Ap[2] = {A0, A1};
  const float* Wp[2] = {W0, W1};
  int Kp[2] = {K0, K1};
  #pragma unroll
  for (int p = 0; p < NPAIR; ++p) {
    const float* A = Ap[p]; const float* W = Wp[p]; int K = Kp[p];
    for (int k0 = 0; k0 < K; k0 += 32) {
      __syncthreads();
      // stage A: 64 rows x 32 k, stored transposed
      #pragma unroll
      for (int i = 0; i < 2; ++i) {
        int fid = threadIdx.x + i * 256;
        int row = fid >> 3, kq = fid & 7;
        int gr = n0 + row; gr = (gr < N) ? gr : (N - 1);
        float4 v = *(const float4*)(A + (long long)gr * K + k0 + kq * 4);
        AsT[kq * 4 + 0][row] = v.x; AsT[kq * 4 + 1][row] = v.y;
        AsT[kq * 4 + 2][row] = v.z; AsT[kq * 4 + 3][row] = v.w;
      }
      // stage B: 32 k x 64 m
      #pragma unroll
      for (int i = 0; i < 2; ++i) {
        int fid = threadIdx.x + i * 256;
        int kr = fid >> 4, mq = fid & 15;
        *(float4*)&Bs[kr][mq * 4] =
            *(const float4*)(W + (long long)(k0 + kr) * M + m0 + mq * 4);
      }
      __syncthreads();
      #pragma unroll
      for (int kk = 0; kk < 32; ++kk) {
        float4 af = *(const float4*)&AsT[kk][ty * 4];
        float4 bf = *(const float4*)&Bs[kk][tx * 4];
        float a[4] = {af.x, af.y, af.z, af.w};
        float b[4] = {bf.x, bf.y, bf.z, bf.w};
        #pragma unroll
        for (int r = 0; r < 4; ++r)
          #pragma unroll
          for (int c = 0; c < 4; ++c)
            acc[r][c] = fmaf(a[r], b[c], acc[r][c]);
      }
    }
  }
  float4 bv = *(const float4*)&bias[m0 + tx * 4];
  float bb[4] = {bv.x, bv.y, bv.z, bv.w};
  #pragma unroll
  for (int r = 0; r < 4; ++r) {
    int row = n0 + ty * 4 + r;
    if (row < N) {
      float4 o;
      o.x = acc[r][0] + bb[0]; o.y = acc[r][1] + bb[1];
      o.z = acc[r][2] + bb[2]; o.w = acc[r][3] + bb[3];
      if (RELU) {
        o.x = fmaxf(o.x, 0.f); o.y = fmaxf(o.y, 0.f);
        o.z = fmaxf(o.z, 0.f); o.w = fmaxf(o.w, 0.f);
      }
      *(float4*)&out[(long long)row * M + m0 + tx * 4] = o;
    }
  }
}

// ================= fused GATv2: score+softmax+aggregate+mean+bias+relu =================
__global__ __launch_bounds__(512) void k_gatv2_fused(
    const float* __restrict__ xl, const float* __restrict__ xr,
    const int* __restrict__ rowptr, const int* __restrict__ srcid,
    const float* __restrict__ att, const float* __restrict__ bias,
    float* __restrict__ out) {
  int d = blockIdx.x;
  int h = threadIdx.x >> 6;
  int lane = threadIdx.x & 63;
  __shared__ float red[8][128];

  const float* pr = xr + (long long)d * 1024 + h * C2;
  float xr0 = pr[lane], xr1 = pr[lane + 64];
  float a0 = att[h * C2 + lane], a1 = att[h * C2 + lane + 64];

  float m = -INFINITY, s = 0.f, acc0 = 0.f, acc1 = 0.f;
  int b = rowptr[d], e = rowptr[d + 1];
  for (int i = b; i < e; ++i) {
    const float* pl = xl + (long long)srcid[i] * 1024 + h * C2;
    float x0 = pl[lane], x1 = pl[lane + 64];
    float t0 = x0 + xr0; t0 = (t0 > 0.f) ? t0 : NEG * t0;
    float t1 = x1 + xr1; t1 = (t1 > 0.f) ? t1 : NEG * t1;
    float v = fmaf(t0, a0, t1 * a1);
    #pragma unroll
    for (int o = 32; o; o >>= 1) v += __shfl_xor(v, o);
    if (v > m) {
      float sc = __expf(m - v);
      s *= sc; acc0 *= sc; acc1 *= sc; m = v;
    }
    float a = __expf(v - m);
    s += a;
    acc0 = fmaf(a, x0, acc0);
    acc1 = fmaf(a, x1, acc1);
  }
  float inv = (s > 0.f) ? 1.f / s : 0.f;
  red[h][lane] = acc0 * inv;
  red[h][lane + 64] = acc1 * inv;
  __syncthreads();
  if (threadIdx.x < C2) {
    int c = threadIdx.x;
    float v = 0.f;
    #pragma unroll
    for (int hh = 0; hh < HH; ++hh) v += red[hh][c];
    v = v * 0.125f + bias[c];
    out[(long long)d * C2 + c] = fmaxf(v, 0.f);
  }
}

// ================= classifier =================
__global__ void k_dot64(const float* __restrict__ xs, const float* __restrict__ xd,
                        const int* __restrict__ ls, const int* __restrict__ ld,
                        float* __restrict__ out, int L) {
  long long t = (long long)blockIdx.x * blockDim.x + threadIdx.x;
  int gw = (int)(t >> 6), lane = (int)(t & 63);
  if (gw >= L) return;
  float v = xs[(long long)ls[gw] * 64 + lane] * xd[(long long)ld[gw] * 64 + lane];
  #pragma unroll
  for (int off = 32; off; off >>= 1) v += __shfl_down(v, off);
  if (lane == 0) out[gw] = v;
}

extern "C" void kernel_launch(void* const* d_in, const int* in_sizes, int n_in,
                              void* d_out, int out_size, void* d_ws, size_t ws_size,
                              hipStream_t stream) {
  const float* x_s = (const float*)d_in[0];
  const float* x_d = (const float*)d_in[1];
  const int* esrc = (const int*)d_in[2];
  const int* edst = (const int*)d_in[3];
  const int* lsrc = (const int*)d_in[4];
  const int* ldst = (const int*)d_in[5];
  const float* W1rel_sd  = (const float*)d_in[6];
  const float* b1_sd     = (const float*)d_in[7];
  const float* W1root_sd = (const float*)d_in[8];
  const float* W1rel_ds  = (const float*)d_in[9];
  const float* b1_ds     = (const float*)d_in[10];
  const float* W1root_ds = (const float*)d_in[11];
  const float *Wl2_sd = (const float*)d_in[12], *bl2_sd = (const float*)d_in[13],
              *Wr2_sd = (const float*)d_in[14], *br2_sd = (const float*)d_in[15],
              *att2_sd = (const float*)d_in[16], *bias2_sd = (const float*)d_in[17];
  const float *Wl2_ds = (const float*)d_in[18], *bl2_ds = (const float*)d_in[19],
              *Wr2_ds = (const float*)d_in[20], *br2_ds = (const float*)d_in[21],
              *att2_ds = (const float*)d_in[22], *bias2_ds = (const float*)d_in[23];
  const float *W3rel_sd = (const float*)d_in[24], *b3_sd = (const float*)d_in[25],
              *W3root_sd = (const float*)d_in[26];
  const float *W3rel_ds = (const float*)d_in[27], *b3_ds = (const float*)d_in[28],
              *W3root_ds = (const float*)d_in[29];
  float* out = (float*)d_out;

  // ---- workspace arena ----
  float* w = (float*)d_ws;
  long long off = 0;
  auto alloc = [&](long long n) { float* p = w + off; off += (n + 63) & ~63LL; return p; };
  float* XS1   = alloc((long long)N_S * 128);
  float* XD1   = alloc((long long)N_D * 128);
  float* XS2   = alloc((long long)N_S * 128);
  float* XD2   = alloc((long long)N_D * 128);
  float* XS3   = alloc((long long)N_S * 64);
  float* XD3   = alloc((long long)N_D * 64);
  float* AGG_S = alloc((long long)N_S * 128);
  float* AGG_D = alloc((long long)N_D * 128);
  int* rowptr_d = (int*)alloc(N_D + 64);
  int* rowptr_s = (int*)alloc(N_S + 64);
  int* cur_d    = (int*)alloc(N_D + 64);
  int* cur_s    = (int*)alloc(N_S + 64);
  int* csrc_d   = (int*)alloc(E_N);
  int* csrc_s   = (int*)alloc(E_N);
  float* BIG    = alloc(22528000LL);
  (void)ws_size; (void)in_sizes; (void)n_in; (void)out_size;

  // ================= build CSR both directions =================
  hipMemsetAsync(cur_d, 0, (size_t)N_D * 4, stream);
  hipMemsetAsync(cur_s, 0, (size_t)N_S * 4, stream);
  k_hist<<<(E_N + 255) / 256, 256, 0, stream>>>(edst, cur_d, E_N);
  k_hist<<<(E_N + 255) / 256, 256, 0, stream>>>(esrc, cur_s, E_N);
  k_scan<<<1, 1024, 0, stream>>>(cur_d, rowptr_d, N_D);
  k_scan<<<1, 1024, 0, stream>>>(cur_s, rowptr_s, N_S);
  hipMemcpyAsync(cur_d, rowptr_d, (size_t)N_D * 4, hipMemcpyDeviceToDevice, stream);
  hipMemcpyAsync(cur_s, rowptr_s, (size_t)N_S * 4, hipMemcpyDeviceToDevice, stream);
  k_csr_scatter<<<(E_N + 255) / 256, 256, 0, stream>>>(edst, esrc, cur_d, csrc_d, E_N);
  k_csr_scatter<<<(E_N + 255) / 256, 256, 0, stream>>>(esrc, edst, cur_s, csrc_s, E_N);

  // ================= layer 1: GraphConv =================
  k_csr_gather_sum<128><<<N_D, 128, 0, stream>>>(x_s, rowptr_d, csrc_d, AGG_D);
  k_csr_gather_sum<64><<<N_S, 64, 0, stream>>>(x_d, rowptr_s, csrc_s, AGG_S);
  k_gemm<1, 2><<<dim3(2, 32), 256, 0, stream>>>(
      AGG_D, W1rel_sd, 128, x_d, W1root_sd, 64, b1_sd, XD1, N_D, 128);
  k_gemm<1, 2><<<dim3(2, 157), 256, 0, stream>>>(
      AGG_S, W1rel_ds, 64, x_s, W1root_ds, 128, b1_ds, XS1, N_S, 128);

  // ================= layer 2: GATv2 =================
  auto gat = [&](const float* xsrc, int Nsrc, const float* xdst, int Ndst,
                 const int* rowptr, const int* srcid,
                 const float* Wl, const float* bl, const float* Wr, const float* br,
                 const float* att, const float* bias, float* outv) {
    float* XL = BIG;
    float* XR = BIG + (long long)Nsrc * 1024;
    k_gemm<0, 1><<<dim3(16, (Nsrc + 63) / 64), 256, 0, stream>>>(
        xsrc, Wl, 128, nullptr, nullptr, 0, bl, XL, Nsrc, 1024);
    k_gemm<0, 1><<<dim3(16, (Ndst + 63) / 64), 256, 0, stream>>>(
        xdst, Wr, 128, nullptr, nullptr, 0, br, XR, Ndst, 1024);
    k_gatv2_fused<<<Ndst, 512, 0, stream>>>(XL, XR, rowptr, srcid, att, bias, outv);
  };
  gat(XS1, N_S, XD1, N_D, rowptr_d, csrc_d,
      Wl2_sd, bl2_sd, Wr2_sd, br2_sd, att2_sd, bias2_sd, XD2);
  gat(XD1, N_D, XS1, N_S, rowptr_s, csrc_s,
      Wl2_ds, bl2_ds, Wr2_ds, br2_ds, att2_ds, bias2_ds, XS2);

  // ================= layer 3: GraphConv =================
  k_csr_gather_sum<128><<<N_D, 128, 0, stream>>>(XS2, rowptr_d, csrc_d, AGG_D);
  k_csr_gather_sum<128><<<N_S, 128, 0, stream>>>(XD2, rowptr_s, csrc_s, AGG_S);
  k_gemm<0, 2><<<dim3(1, 32), 256, 0, stream>>>(
      AGG_D, W3rel_sd, 128, XD2, W3root_sd, 128, b3_sd, XD3, N_D, 64);
  k_gemm<0, 2><<<dim3(1, 157), 256, 0, stream>>>(
      AGG_S, W3rel_ds, 128, XS2, W3root_ds, 128, b3_ds, XS3, N_S, 64);

  // ================= classifier =================
  long long tw = (long long)L_N * 64;
  k_dot64<<<(int)((tw + 255) / 256), 256, 0, stream>>>(XS3, XD3, lsrc, ldst, out, L_N);
}

// Round 4
// 307.620 us; speedup vs baseline: 6.6964x; 1.4456x over previous
//
#include <hip/hip_runtime.h>
#include <math.h>

#define HH 8
#define C2 128
#define NEG 0.2f

static const int N_S = 10000, N_D = 2000, E_N = 100000, L_N = 50000;

using short8 = __attribute__((ext_vector_type(8))) short;
using f32x4  = __attribute__((ext_vector_type(4))) float;

__device__ inline unsigned short f2bf(float f) {
  unsigned u = __float_as_uint(f);
  u += 0x7fff + ((u >> 16) & 1);          // round-to-nearest-even
  return (unsigned short)(u >> 16);
}
__device__ inline void unpack16(uint4 u0, uint4 u1, float* x) {
  x[0]  = __uint_as_float(u0.x << 16); x[1]  = __uint_as_float(u0.x & 0xffff0000u);
  x[2]  = __uint_as_float(u0.y << 16); x[3]  = __uint_as_float(u0.y & 0xffff0000u);
  x[4]  = __uint_as_float(u0.z << 16); x[5]  = __uint_as_float(u0.z & 0xffff0000u);
  x[6]  = __uint_as_float(u0.w << 16); x[7]  = __uint_as_float(u0.w & 0xffff0000u);
  x[8]  = __uint_as_float(u1.x << 16); x[9]  = __uint_as_float(u1.x & 0xffff0000u);
  x[10] = __uint_as_float(u1.y << 16); x[11] = __uint_as_float(u1.y & 0xffff0000u);
  x[12] = __uint_as_float(u1.z << 16); x[13] = __uint_as_float(u1.z & 0xffff0000u);
  x[14] = __uint_as_float(u1.w << 16); x[15] = __uint_as_float(u1.w & 0xffff0000u);
}

// ================= CSR build =================
__global__ void k_hist(const int* __restrict__ key, int* __restrict__ deg, int E) {
  int e = blockIdx.x * 256 + threadIdx.x;
  if (e < E) atomicAdd(&deg[key[e]], 1);
}

__global__ void k_scan(const int* __restrict__ deg, int* __restrict__ rowptr, int N) {
  __shared__ int buf[1024];
  __shared__ int carry;
  if (threadIdx.x == 0) carry = 0;
  __syncthreads();
  for (int base = 0; base < N; base += 1024) {
    int i = base + threadIdx.x;
    int v = (i < N) ? deg[i] : 0;
    buf[threadIdx.x] = v;
    __syncthreads();
    for (int st = 1; st < 1024; st <<= 1) {
      int t = (threadIdx.x >= st) ? buf[threadIdx.x - st] : 0;
      __syncthreads();
      buf[threadIdx.x] += t;
      __syncthreads();
    }
    int incl = buf[threadIdx.x];
    if (i < N) rowptr[i] = carry + incl - v;
    int total = buf[1023];
    __syncthreads();
    if (threadIdx.x == 0) {
      if (base + 1024 >= N) rowptr[N] = carry + total;
      carry += total;
    }
    __syncthreads();
  }
}

__global__ void k_csr_scatter(const int* __restrict__ key, const int* __restrict__ val,
                              int* __restrict__ cursor, int* __restrict__ csrc, int E) {
  int e = blockIdx.x * 256 + threadIdx.x;
  if (e >= E) return;
  int pos = atomicAdd(&cursor[key[e]], 1);
  csrc[pos] = val[e];
}

// ================= CSR gather-sum =================
template<int C>
__global__ void k_csr_gather_sum(const float* __restrict__ x, const int* __restrict__ rowptr,
                                 const int* __restrict__ src, float* __restrict__ out) {
  int n = blockIdx.x;
  int c = threadIdx.x;
  int b = rowptr[n], e = rowptr[n + 1];
  float acc = 0.f;
  int i = b;
  for (; i + 1 < e; i += 2) {
    float v0 = x[(long long)src[i] * C + c];
    float v1 = x[(long long)src[i + 1] * C + c];
    acc += v0 + v1;
  }
  if (i < e) acc += x[(long long)src[i] * C + c];
  out[(long long)n * C + c] = acc;
}

// ================= tiled fp32 GEMM (layers 1 & 3) =================
// out = [relu]( sum_p A_p@W_p + bias ); OUTBF: emit bf16 instead of fp32
template<int RELU, int NPAIR, int OUTBF>
__global__ __launch_bounds__(256) void k_gemm(
    const float* __restrict__ A0, const float* __restrict__ W0, int K0,
    const float* __restrict__ A1, const float* __restrict__ W1, int K1,
    const float* __restrict__ bias, void* __restrict__ outp, int N, int M) {
  __shared__ float AsT[32][68];
  __shared__ float Bs[32][68];
  int tx = threadIdx.x & 15, ty = threadIdx.x >> 4;
  int m0 = blockIdx.x * 64, n0 = blockIdx.y * 64;
  float acc[4][4] = {};
  const float* Ap[2] = {A0, A1};
  const float* Wp[2] = {W0, W1};
  int Kp[2] = {K0, K1};
  #pragma unroll
  for (int p = 0; p < NPAIR; ++p) {
    const float* A = Ap[p]; const float* W = Wp[p]; int K = Kp[p];
    for (int k0 = 0; k0 < K; k0 += 32) {
      __syncthreads();
      #pragma unroll
      for (int i = 0; i < 2; ++i) {
        int fid = threadIdx.x + i * 256;
        int row = fid >> 3, kq = fid & 7;
        int gr = n0 + row; gr = (gr < N) ? gr : (N - 1);
        float4 v = *(const float4*)(A + (long long)gr * K + k0 + kq * 4);
        AsT[kq * 4 + 0][row] = v.x; AsT[kq * 4 + 1][row] = v.y;
        AsT[kq * 4 + 2][row] = v.z; AsT[kq * 4 + 3][row] = v.w;
      }
      #pragma unroll
      for (int i = 0; i < 2; ++i) {
        int fid = threadIdx.x + i * 256;
        int kr = fid >> 4, mq = fid & 15;
        *(float4*)&Bs[kr][mq * 4] =
            *(const float4*)(W + (long long)(k0 + kr) * M + m0 + mq * 4);
      }
      __syncthreads();
      #pragma unroll
      for (int kk = 0; kk < 32; ++kk) {
        float4 af = *(const float4*)&AsT[kk][ty * 4];
        float4 bf = *(const float4*)&Bs[kk][tx * 4];
        float a[4] = {af.x, af.y, af.z, af.w};
        float b[4] = {bf.x, bf.y, bf.z, bf.w};
        #pragma unroll
        for (int r = 0; r < 4; ++r)
          #pragma unroll
          for (int c = 0; c < 4; ++c)
            acc[r][c] = fmaf(a[r], b[c], acc[r][c]);
      }
    }
  }
  float4 bv = *(const float4*)&bias[m0 + tx * 4];
  float bb[4] = {bv.x, bv.y, bv.z, bv.w};
  #pragma unroll
  for (int r = 0; r < 4; ++r) {
    int row = n0 + ty * 4 + r;
    if (row < N) {
      float o[4];
      #pragma unroll
      for (int c = 0; c < 4; ++c) {
        o[c] = acc[r][c] + bb[c];
        if (RELU) o[c] = fmaxf(o[c], 0.f);
      }
      if (OUTBF) {
        ushort4 ob = {f2bf(o[0]), f2bf(o[1]), f2bf(o[2]), f2bf(o[3])};
        *(ushort4*)&((unsigned short*)outp)[(long long)row * M + m0 + tx * 4] = ob;
      } else {
        float4 of = {o[0], o[1], o[2], o[3]};
        *(float4*)&((float*)outp)[(long long)row * M + m0 + tx * 4] = of;
      }
    }
  }
}

// ================= weight pack: W[K,1024] fp32 -> MFMA B-fragment bf16 =================
// P[((kt*64+ct)*64+l)*8+r] = bf16( W[(kt*32+(l>>4)*8+r)][ct*16+(l&15)] )
__global__ void k_pack_w(const float* __restrict__ W, unsigned short* __restrict__ P) {
  int tid = blockIdx.x * 256 + threadIdx.x;   // < 4*64*64*8 = 131072
  int r = tid & 7, l = (tid >> 3) & 63, ct = (tid >> 9) & 63, kt = tid >> 15;
  int k = kt * 32 + (l >> 4) * 8 + r;
  int col = ct * 16 + (l & 15);
  P[tid] = f2bf(W[k * 1024 + col]);
}

// ================= MFMA bf16 GEMM: out[N,1024] = bf16( A[N,128]@W + bias ) ======
__global__ __launch_bounds__(256) void k_gemm_mfma(
    const unsigned short* __restrict__ A, const unsigned short* __restrict__ Bp,
    const float* __restrict__ bias, unsigned short* __restrict__ out, int N) {
  int w = threadIdx.x >> 6, l = threadIdx.x & 63;
  int c0 = blockIdx.x * 64;
  int r0 = blockIdx.y * 64 + w * 16;
  int lg = l >> 4, lo = l & 15;
  f32x4 acc[4] = {};
  int arow = r0 + lo; arow = (arow < N) ? arow : (N - 1);
  const unsigned short* ab = A + (long long)arow * 128 + lg * 8;
  #pragma unroll
  for (int kt = 0; kt < 4; ++kt) {
    short8 a = *(const short8*)(ab + kt * 32);
    #pragma unroll
    for (int ct = 0; ct < 4; ++ct) {
      short8 b = *(const short8*)(Bp + (((kt * 64) + (c0 >> 4) + ct) * 64 + l) * 8);
      acc[ct] = __builtin_amdgcn_mfma_f32_16x16x32_bf16(a, b, acc[ct], 0, 0, 0);
    }
  }
  #pragma unroll
  for (int ct = 0; ct < 4; ++ct) {
    int col = c0 + ct * 16 + lo;
    float bv = bias[col];
    #pragma unroll
    for (int r = 0; r < 4; ++r) {
      int grow = r0 + lg * 4 + r;
      if (grow < N) out[(long long)grow * 1024 + col] = f2bf(acc[ct][r] + bv);
    }
  }
}

// ================= fused GATv2: all 8 heads per wave, bf16 XL/XR =================
template<int WPN>   // waves cooperating per dst node (1 or 4)
__global__ __launch_bounds__(256) void k_gatv2(
    const unsigned short* __restrict__ xl, const unsigned short* __restrict__ xr,
    const int* __restrict__ rowptr, const int* __restrict__ srcid,
    const float* __restrict__ att, const float* __restrict__ bias,
    float* __restrict__ out, int Ndst) {
  int widx = threadIdx.x >> 6;
  int l = threadIdx.x & 63;
  int node, wsub;
  if (WPN == 4) { node = blockIdx.x; wsub = widx; }
  else         { node = blockIdx.x * 4 + widx; wsub = 0; }
  if (WPN == 1 && node >= Ndst) return;
  int h = l >> 3, sub = l & 7;
  int cbase = h * 128 + sub * 16;

  float xrv[16], atv[16];
  {
    const uint4* p = (const uint4*)(xr + (long long)node * 1024 + cbase);
    unpack16(p[0], p[1], xrv);
    const float4* pa = (const float4*)(att + cbase);
    float4 a0 = pa[0], a1 = pa[1], a2 = pa[2], a3 = pa[3];
    atv[0] = a0.x; atv[1] = a0.y; atv[2] = a0.z; atv[3] = a0.w;
    atv[4] = a1.x; atv[5] = a1.y; atv[6] = a1.z; atv[7] = a1.w;
    atv[8] = a2.x; atv[9] = a2.y; atv[10] = a2.z; atv[11] = a2.w;
    atv[12] = a3.x; atv[13] = a3.y; atv[14] = a3.z; atv[15] = a3.w;
  }

  float m = -INFINITY, s = 0.f, acc[16] = {};
  int b = rowptr[node], e = rowptr[node + 1];

  auto process = [&](uint4 u0, uint4 u1) {
    float x[16];
    unpack16(u0, u1, x);
    float sc = 0.f;
    #pragma unroll
    for (int j = 0; j < 16; ++j) {
      float t = x[j] + xrv[j];
      t = fmaxf(t, NEG * t);            // leaky relu
      sc = fmaf(t, atv[j], sc);
    }
    sc += __shfl_xor(sc, 1); sc += __shfl_xor(sc, 2); sc += __shfl_xor(sc, 4);
    if (sc > m + 8.f) {                  // defer-rescale (T13)
      float scl = __expf(m - sc);
      s *= scl;
      #pragma unroll
      for (int j = 0; j < 16; ++j) acc[j] *= scl;
      m = sc;
    }
    float a = __expf(sc - m);
    s += a;
    #pragma unroll
    for (int j = 0; j < 16; ++j) acc[j] = fmaf(a, x[j], acc[j]);
  };

  int i = b + wsub;
  for (; i + WPN < e; i += 2 * WPN) {
    const uint4* p0 = (const uint4*)(xl + (long long)srcid[i] * 1024 + cbase);
    const uint4* p1 = (const uint4*)(xl + (long long)srcid[i + WPN] * 1024 + cbase);
    uint4 a0 = p0[0], a1 = p0[1], b0 = p1[0], b1 = p1[1];
    process(a0, a1);
    process(b0, b1);
  }
  if (i < e) {
    const uint4* p0 = (const uint4*)(xl + (long long)srcid[i] * 1024 + cbase);
    process(p0[0], p0[1]);
  }

  float val[16];
  if constexpr (WPN == 4) {
    __shared__ float lm[4][8], lss[4][8];
    __shared__ float lacc[4][64][16];
    if (sub == 0) { lm[wsub][h] = m; lss[wsub][h] = s; }
    #pragma unroll
    for (int q = 0; q < 4; ++q) {
      float4 t = {acc[q * 4], acc[q * 4 + 1], acc[q * 4 + 2], acc[q * 4 + 3]};
      *(float4*)&lacc[wsub][l][q * 4] = t;
    }
    __syncthreads();
    if (wsub != 0) return;
    float M2 = fmaxf(fmaxf(lm[0][h], lm[1][h]), fmaxf(lm[2][h], lm[3][h]));
    float S = 0.f;
    #pragma unroll
    for (int j = 0; j < 16; ++j) val[j] = 0.f;
    #pragma unroll
    for (int w2 = 0; w2 < 4; ++w2) {
      float scw = (M2 == -INFINITY) ? 0.f : __expf(lm[w2][h] - M2);
      S = fmaf(scw, lss[w2][h], S);
      #pragma unroll
      for (int j = 0; j < 16; ++j) val[j] = fmaf(scw, lacc[w2][l][j], val[j]);
    }
    float inv = (S > 0.f) ? 1.f / S : 0.f;
    #pragma unroll
    for (int j = 0; j < 16; ++j) val[j] *= inv;
  } else {
    float inv = (s > 0.f) ? 1.f / s : 0.f;
    #pragma unroll
    for (int j = 0; j < 16; ++j) val[j] = acc[j] * inv;
  }
  // head mean across lane strides 8,16,32
  #pragma unroll
  for (int j = 0; j < 16; ++j) {
    val[j] += __shfl_xor(val[j], 8);
    val[j] += __shfl_xor(val[j], 16);
    val[j] += __shfl_xor(val[j], 32);
  }
  if (l < 8) {
    #pragma unroll
    for (int q = 0; q < 4; ++q) {
      float4 bq = *(const float4*)&bias[sub * 16 + q * 4];
      float4 o;
      o.x = fmaxf(val[q * 4 + 0] * 0.125f + bq.x, 0.f);
      o.y = fmaxf(val[q * 4 + 1] * 0.125f + bq.y, 0.f);
      o.z = fmaxf(val[q * 4 + 2] * 0.125f + bq.z, 0.f);
      o.w = fmaxf(val[q * 4 + 3] * 0.125f + bq.w, 0.f);
      *(float4*)&out[(long long)node * C2 + sub * 16 + q * 4] = o;
    }
  }
}

// ================= classifier =================
__global__ void k_dot64(const float* __restrict__ xs, const float* __restrict__ xd,
                        const int* __restrict__ ls, const int* __restrict__ ld,
                        float* __restrict__ out, int L) {
  long long t = (long long)blockIdx.x * blockDim.x + threadIdx.x;
  int gw = (int)(t >> 6), lane = (int)(t & 63);
  if (gw >= L) return;
  float v = xs[(long long)ls[gw] * 64 + lane] * xd[(long long)ld[gw] * 64 + lane];
  #pragma unroll
  for (int off = 32; off; off >>= 1) v += __shfl_down(v, off);
  if (lane == 0) out[gw] = v;
}

extern "C" void kernel_launch(void* const* d_in, const int* in_sizes, int n_in,
                              void* d_out, int out_size, void* d_ws, size_t ws_size,
                              hipStream_t stream) {
  const float* x_s = (const float*)d_in[0];
  const float* x_d = (const float*)d_in[1];
  const int* esrc = (const int*)d_in[2];
  const int* edst = (const int*)d_in[3];
  const int* lsrc = (const int*)d_in[4];
  const int* ldst = (const int*)d_in[5];
  const float* W1rel_sd  = (const float*)d_in[6];
  const float* b1_sd     = (const float*)d_in[7];
  const float* W1root_sd = (const float*)d_in[8];
  const float* W1rel_ds  = (const float*)d_in[9];
  const float* b1_ds     = (const float*)d_in[10];
  const float* W1root_ds = (const float*)d_in[11];
  const float *Wl2_sd = (const float*)d_in[12], *bl2_sd = (const float*)d_in[13],
              *Wr2_sd = (const float*)d_in[14], *br2_sd = (const float*)d_in[15],
              *att2_sd = (const float*)d_in[16], *bias2_sd = (const float*)d_in[17];
  const float *Wl2_ds = (const float*)d_in[18], *bl2_ds = (const float*)d_in[19],
              *Wr2_ds = (const float*)d_in[20], *br2_ds = (const float*)d_in[21],
              *att2_ds = (const float*)d_in[22], *bias2_ds = (const float*)d_in[23];
  const float *W3rel_sd = (const float*)d_in[24], *b3_sd = (const float*)d_in[25],
              *W3root_sd = (const float*)d_in[26];
  const float *W3rel_ds = (const float*)d_in[27], *b3_ds = (const float*)d_in[28],
              *W3root_ds = (const float*)d_in[29];
  float* out = (float*)d_out;

  // ---- workspace arena (float units) ----
  float* w = (float*)d_ws;
  long long off = 0;
  auto alloc = [&](long long n) { float* p = w + off; off += (n + 63) & ~63LL; return p; };
  float* XS2   = alloc((long long)N_S * 128);
  float* XD2   = alloc((long long)N_D * 128);
  float* XS3   = alloc((long long)N_S * 64);
  float* XD3   = alloc((long long)N_D * 64);
  float* AGG_S = alloc((long long)N_S * 128);
  float* AGG_D = alloc((long long)N_D * 128);
  unsigned short* XS1b = (unsigned short*)alloc((long long)N_S * 64);   // bf16 [N_S,128]
  unsigned short* XD1b = (unsigned short*)alloc((long long)N_D * 64);   // bf16 [N_D,128]
  unsigned short* XLsd = (unsigned short*)alloc((long long)N_S * 512);  // bf16 [N_S,1024]
  unsigned short* XRsd = (unsigned short*)alloc((long long)N_D * 512);
  unsigned short* XLds = (unsigned short*)alloc((long long)N_D * 512);
  unsigned short* XRds = (unsigned short*)alloc((long long)N_S * 512);
  unsigned short* Pk[4];
  for (int i = 0; i < 4; ++i) Pk[i] = (unsigned short*)alloc(65536);
  int* rowptr_d = (int*)alloc(N_D + 64);
  int* rowptr_s = (int*)alloc(N_S + 64);
  int* cur_d    = (int*)alloc(N_D + 64);
  int* cur_s    = (int*)alloc(N_S + 64);
  int* csrc_d   = (int*)alloc(E_N);
  int* csrc_s   = (int*)alloc(E_N);
  (void)ws_size; (void)in_sizes; (void)n_in; (void)out_size;

  // ================= build CSR both directions =================
  hipMemsetAsync(cur_d, 0, (size_t)N_D * 4, stream);
  hipMemsetAsync(cur_s, 0, (size_t)N_S * 4, stream);
  k_hist<<<(E_N + 255) / 256, 256, 0, stream>>>(edst, cur_d, E_N);
  k_hist<<<(E_N + 255) / 256, 256, 0, stream>>>(esrc, cur_s, E_N);
  k_scan<<<1, 1024, 0, stream>>>(cur_d, rowptr_d, N_D);
  k_scan<<<1, 1024, 0, stream>>>(cur_s, rowptr_s, N_S);
  hipMemcpyAsync(cur_d, rowptr_d, (size_t)N_D * 4, hipMemcpyDeviceToDevice, stream);
  hipMemcpyAsync(cur_s, rowptr_s, (size_t)N_S * 4, hipMemcpyDeviceToDevice, stream);
  k_csr_scatter<<<(E_N + 255) / 256, 256, 0, stream>>>(edst, esrc, cur_d, csrc_d, E_N);
  k_csr_scatter<<<(E_N + 255) / 256, 256, 0, stream>>>(esrc, edst, cur_s, csrc_s, E_N);

  // ================= pack GAT projection weights =================
  k_pack_w<<<512, 256, 0, stream>>>(Wl2_sd, Pk[0]);
  k_pack_w<<<512, 256, 0, stream>>>(Wr2_sd, Pk[1]);
  k_pack_w<<<512, 256, 0, stream>>>(Wl2_ds, Pk[2]);
  k_pack_w<<<512, 256, 0, stream>>>(Wr2_ds, Pk[3]);

  // ================= layer 1: GraphConv (emit bf16) =================
  k_csr_gather_sum<128><<<N_D, 128, 0, stream>>>(x_s, rowptr_d, csrc_d, AGG_D);
  k_csr_gather_sum<64><<<N_S, 64, 0, stream>>>(x_d, rowptr_s, csrc_s, AGG_S);
  k_gemm<1, 2, 1><<<dim3(2, 32), 256, 0, stream>>>(
      AGG_D, W1rel_sd, 128, x_d, W1root_sd, 64, b1_sd, XD1b, N_D, 128);
  k_gemm<1, 2, 1><<<dim3(2, 157), 256, 0, stream>>>(
      AGG_S, W1rel_ds, 64, x_s, W1root_ds, 128, b1_ds, XS1b, N_S, 128);

  // ================= layer 2: projections (MFMA) + fused GAT =================
  k_gemm_mfma<<<dim3(16, 157), 256, 0, stream>>>(XS1b, Pk[0], bl2_sd, XLsd, N_S);
  k_gemm_mfma<<<dim3(16, 32),  256, 0, stream>>>(XD1b, Pk[1], br2_sd, XRsd, N_D);
  k_gemm_mfma<<<dim3(16, 32),  256, 0, stream>>>(XD1b, Pk[2], bl2_ds, XLds, N_D);
  k_gemm_mfma<<<dim3(16, 157), 256, 0, stream>>>(XS1b, Pk[3], br2_ds, XRds, N_S);

  k_gatv2<4><<<N_D, 256, 0, stream>>>(XLsd, XRsd, rowptr_d, csrc_d,
                                      att2_sd, bias2_sd, XD2, N_D);
  k_gatv2<1><<<(N_S + 3) / 4, 256, 0, stream>>>(XLds, XRds, rowptr_s, csrc_s,
                                                att2_ds, bias2_ds, XS2, N_S);

  // ================= layer 3: GraphConv =================
  k_csr_gather_sum<128><<<N_D, 128, 0, stream>>>(XS2, rowptr_d, csrc_d, AGG_D);
  k_csr_gather_sum<128><<<N_S, 128, 0, stream>>>(XD2, rowptr_s, csrc_s, AGG_S);
  k_gemm<0, 2, 0><<<dim3(1, 32), 256, 0, stream>>>(
      AGG_D, W3rel_sd, 128, XD2, W3root_sd, 128, b3_sd, XD3, N_D, 64);
  k_gemm<0, 2, 0><<<dim3(1, 157), 256, 0, stream>>>(
      AGG_S, W3rel_ds, 128, XS2, W3root_ds, 128, b3_ds, XS3, N_S, 64);

  // ================= classifier =================
  long long tw = (long long)L_N * 64;
  k_dot64<<<(int)((tw + 255) / 256), 256, 0, stream>>>(XS3, XD3, lsrc, ldst, out, L_N);
}

// Round 5
// 217.307 us; speedup vs baseline: 9.4795x; 1.4156x over previous
//
#include <hip/hip_runtime.h>
#include <math.h>

#define HH 8
#define C2 128
#define NEG 0.2f

static const int N_S = 10000, N_D = 2000, E_N = 100000, L_N = 50000;

using short8 = __attribute__((ext_vector_type(8))) short;
using f32x4  = __attribute__((ext_vector_type(4))) float;

__device__ inline unsigned short f2bf(float f) {
  unsigned u = __float_as_uint(f);
  u += 0x7fff + ((u >> 16) & 1);          // round-to-nearest-even
  return (unsigned short)(u >> 16);
}
__device__ inline float bf2f(unsigned short u) {
  return __uint_as_float((unsigned)u << 16);
}
__device__ inline void unpack16(uint4 u0, uint4 u1, float* x) {
  x[0]  = __uint_as_float(u0.x << 16); x[1]  = __uint_as_float(u0.x & 0xffff0000u);
  x[2]  = __uint_as_float(u0.y << 16); x[3]  = __uint_as_float(u0.y & 0xffff0000u);
  x[4]  = __uint_as_float(u0.z << 16); x[5]  = __uint_as_float(u0.z & 0xffff0000u);
  x[6]  = __uint_as_float(u0.w << 16); x[7]  = __uint_as_float(u0.w & 0xffff0000u);
  x[8]  = __uint_as_float(u1.x << 16); x[9]  = __uint_as_float(u1.x & 0xffff0000u);
  x[10] = __uint_as_float(u1.y << 16); x[11] = __uint_as_float(u1.y & 0xffff0000u);
  x[12] = __uint_as_float(u1.z << 16); x[13] = __uint_as_float(u1.z & 0xffff0000u);
  x[14] = __uint_as_float(u1.w << 16); x[15] = __uint_as_float(u1.w & 0xffff0000u);
}

// ================= CSR build (fused both directions) =================
__global__ void k_hist2(const int* __restrict__ es, const int* __restrict__ ed,
                        int* __restrict__ deg_s, int* __restrict__ deg_d, int E) {
  int e = blockIdx.x * 256 + threadIdx.x;
  if (e < E) {
    atomicAdd(&deg_d[ed[e]], 1);
    atomicAdd(&deg_s[es[e]], 1);
  }
}

// block 0 scans cur_d->rowptr_d, block 1 scans cur_s->rowptr_s; in-place cursor
__global__ __launch_bounds__(1024) void k_scan2(int* c0, int* r0, int n0,
                                                int* c1, int* r1, int n1) {
  int* cur = blockIdx.x ? c1 : c0;
  int* rp  = blockIdx.x ? r1 : r0;
  int N    = blockIdx.x ? n1 : n0;
  __shared__ int wsum[16];
  __shared__ int carry;
  if (threadIdx.x == 0) carry = 0;
  __syncthreads();
  int lane = threadIdx.x & 63, wid = threadIdx.x >> 6;
  for (int base = 0; base < N; base += 1024) {
    int i = base + threadIdx.x;
    int v = (i < N) ? cur[i] : 0;
    int x = v;
    #pragma unroll
    for (int dd = 1; dd < 64; dd <<= 1) {
      int t = __shfl_up(x, dd);
      if (lane >= dd) x += t;
    }
    if (lane == 63) wsum[wid] = x;
    __syncthreads();
    int woff = 0;
    for (int ww = 0; ww < wid; ++ww) woff += wsum[ww];
    int cl = carry;
    int excl = cl + woff + x - v;
    if (i < N) { rp[i] = excl; cur[i] = excl; }
    __syncthreads();
    if (threadIdx.x == 0) {
      int t = 0;
      #pragma unroll
      for (int ww = 0; ww < 16; ++ww) t += wsum[ww];
      if (base + 1024 >= N) rp[N] = carry + t;
      carry += t;
    }
    __syncthreads();
  }
}

__global__ void k_scat2(const int* __restrict__ es, const int* __restrict__ ed,
                        int* __restrict__ cur_d, int* __restrict__ cur_s,
                        int* __restrict__ csrc_d, int* __restrict__ csrc_s, int E) {
  int e = blockIdx.x * 256 + threadIdx.x;
  if (e >= E) return;
  int s = es[e], d = ed[e];
  csrc_d[atomicAdd(&cur_d[d], 1)] = s;
  csrc_s[atomicAdd(&cur_s[s], 1)] = d;
}

// ================= input fp32 -> bf16 =================
__global__ void k_cvt(const float* __restrict__ xs, const float* __restrict__ xd,
                      unsigned short* __restrict__ xsb, unsigned short* __restrict__ xdb) {
  int i = blockIdx.x * 256 + threadIdx.x;
  const int ns4 = N_S * 128 / 4, nd4 = N_D * 64 / 4;
  if (i < ns4) {
    float4 v = ((const float4*)xs)[i];
    ushort4 o = {f2bf(v.x), f2bf(v.y), f2bf(v.z), f2bf(v.w)};
    ((ushort4*)xsb)[i] = o;
  } else if (i < ns4 + nd4) {
    int j = i - ns4;
    float4 v = ((const float4*)xd)[j];
    ushort4 o = {f2bf(v.x), f2bf(v.y), f2bf(v.z), f2bf(v.w)};
    ((ushort4*)xdb)[j] = o;
  }
}

// ================= pack fp32 W[K,M] -> bf16 MFMA B-fragments (12 weights) ======
struct PkD { const float* W; unsigned short* P; int K, M; };
struct Pk12 { PkD d[12]; };
__global__ void k_pack(Pk12 g) {
  PkD d = g.d[blockIdx.y];
  int total = d.K * d.M;
  int mt = d.M >> 4;
  for (int tid = blockIdx.x * 256 + threadIdx.x; tid < total; tid += gridDim.x * 256) {
    int r = tid & 7, l = (tid >> 3) & 63;
    int rest = tid >> 9;
    int ct = rest % mt, kt = rest / mt;
    int k = kt * 32 + (l >> 4) * 8 + r;
    int col = ct * 16 + (l & 15);
    d.P[tid] = f2bf(d.W[k * d.M + col]);
  }
}

// ================= CSR gather-sum, bf16 in -> bf16 out, layer 1 ==============
__global__ __launch_bounds__(128) void k_gather_l1(
    const unsigned short* __restrict__ xsb, const unsigned short* __restrict__ xdb,
    const int* __restrict__ rpd, const int* __restrict__ csd,
    const int* __restrict__ rps, const int* __restrict__ css,
    unsigned short* __restrict__ aggd, unsigned short* __restrict__ aggs) {
  if (blockIdx.x < N_D) {
    int n = blockIdx.x, c = threadIdx.x;
    int b = rpd[n], e = rpd[n + 1];
    float acc = 0.f;
    int i = b;
    for (; i + 1 < e; i += 2)
      acc += bf2f(xsb[(long long)csd[i] * 128 + c]) +
             bf2f(xsb[(long long)csd[i + 1] * 128 + c]);
    if (i < e) acc += bf2f(xsb[(long long)csd[i] * 128 + c]);
    aggd[(long long)n * 128 + c] = f2bf(acc);
  } else {
    int n = (blockIdx.x - N_D) * 2 + (threadIdx.x >> 6);
    int c = threadIdx.x & 63;
    if (n >= N_S) return;
    int b = rps[n], e = rps[n + 1];
    float acc = 0.f;
    int i = b;
    for (; i + 1 < e; i += 2)
      acc += bf2f(xdb[(long long)css[i] * 64 + c]) +
             bf2f(xdb[(long long)css[i + 1] * 64 + c]);
    if (i < e) acc += bf2f(xdb[(long long)css[i] * 64 + c]);
    aggs[(long long)n * 64 + c] = f2bf(acc);
  }
}

// ================= CSR gather-sum, layer 3 (C=128 both) ==============
__global__ __launch_bounds__(128) void k_gather_l3(
    const unsigned short* __restrict__ xs2b, const unsigned short* __restrict__ xd2b,
    const int* __restrict__ rpd, const int* __restrict__ csd,
    const int* __restrict__ rps, const int* __restrict__ css,
    unsigned short* __restrict__ aggd, unsigned short* __restrict__ aggs) {
  int c = threadIdx.x;
  if (blockIdx.x < N_D) {
    int n = blockIdx.x;
    int b = rpd[n], e = rpd[n + 1];
    float acc = 0.f;
    int i = b;
    for (; i + 1 < e; i += 2)
      acc += bf2f(xs2b[(long long)csd[i] * 128 + c]) +
             bf2f(xs2b[(long long)csd[i + 1] * 128 + c]);
    if (i < e) acc += bf2f(xs2b[(long long)csd[i] * 128 + c]);
    aggd[(long long)n * 128 + c] = f2bf(acc);
  } else {
    int n = blockIdx.x - N_D;
    int b = rps[n], e = rps[n + 1];
    float acc = 0.f;
    int i = b;
    for (; i + 1 < e; i += 2)
      acc += bf2f(xd2b[(long long)css[i] * 128 + c]) +
             bf2f(xd2b[(long long)css[i + 1] * 128 + c]);
    if (i < e) acc += bf2f(xd2b[(long long)css[i] * 128 + c]);
    aggs[(long long)n * 128 + c] = f2bf(acc);
  }
}

// ================= generic fused MFMA GEMM (descriptor per blockIdx.y range) ======
// out = [relu]( A0@W0 + [A1@W1] + bias ), bf16 or fp32 out
struct GD {
  const unsigned short *A0, *P0, *A1, *P1;
  const float* bias;
  void* out;
  int K0, K1, N, M, relu, outbf, y0;
};
template<int ND> struct GDs { GD d[ND]; };

template<int ND>
__global__ __launch_bounds__(256) void k_mfma(GDs<ND> g) {
  int by = blockIdx.y;
  int di = 0;
  #pragma unroll
  for (int i = 1; i < ND; ++i) if (by >= g.d[i].y0) di = i;
  GD d = g.d[di];
  int ytile = by - d.y0;
  int c0 = blockIdx.x * 64;
  if (c0 >= d.M) return;
  int w = threadIdx.x >> 6, l = threadIdx.x & 63;
  int r0 = ytile * 64 + w * 16;
  if (r0 >= d.N) return;
  int lg = l >> 4, lo = l & 15;
  f32x4 acc[4] = {};
  int arow = r0 + lo; arow = (arow < d.N) ? arow : (d.N - 1);
  int mt = d.M >> 4;
  int ct0 = c0 >> 4;
  const unsigned short* a0 = d.A0 + (long long)arow * d.K0 + lg * 8;
  for (int kt = 0; kt < (d.K0 >> 5); ++kt) {
    short8 a = *(const short8*)(a0 + kt * 32);
    #pragma unroll
    for (int ct = 0; ct < 4; ++ct) {
      short8 b = *(const short8*)(d.P0 + ((long long)(kt * mt + ct0 + ct) * 64 + l) * 8);
      acc[ct] = __builtin_amdgcn_mfma_f32_16x16x32_bf16(a, b, acc[ct], 0, 0, 0);
    }
  }
  if (d.K1) {
    const unsigned short* a1 = d.A1 + (long long)arow * d.K1 + lg * 8;
    for (int kt = 0; kt < (d.K1 >> 5); ++kt) {
      short8 a = *(const short8*)(a1 + kt * 32);
      #pragma unroll
      for (int ct = 0; ct < 4; ++ct) {
        short8 b = *(const short8*)(d.P1 + ((long long)(kt * mt + ct0 + ct) * 64 + l) * 8);
        acc[ct] = __builtin_amdgcn_mfma_f32_16x16x32_bf16(a, b, acc[ct], 0, 0, 0);
      }
    }
  }
  #pragma unroll
  for (int ct = 0; ct < 4; ++ct) {
    int col = c0 + ct * 16 + lo;
    float bv = d.bias[col];
    #pragma unroll
    for (int r = 0; r < 4; ++r) {
      int grow = r0 + lg * 4 + r;
      if (grow < d.N) {
        float v = acc[ct][r] + bv;
        if (d.relu) v = fmaxf(v, 0.f);
        if (d.outbf)
          ((unsigned short*)d.out)[(long long)grow * d.M + col] = f2bf(v);
        else
          ((float*)d.out)[(long long)grow * d.M + col] = v;
      }
    }
  }
}

// ================= fused GATv2: all 8 heads per wave, bf16 in/out =================
template<int WPN>
__global__ __launch_bounds__(256) void k_gatv2(
    const unsigned short* __restrict__ xl, const unsigned short* __restrict__ xr,
    const int* __restrict__ rowptr, const int* __restrict__ srcid,
    const float* __restrict__ att, const float* __restrict__ bias,
    unsigned short* __restrict__ outb, int Ndst) {
  int widx = threadIdx.x >> 6;
  int l = threadIdx.x & 63;
  int node, wsub;
  if (WPN == 4) { node = blockIdx.x; wsub = widx; }
  else         { node = blockIdx.x * 4 + widx; wsub = 0; }
  if (WPN == 1 && node >= Ndst) return;
  int h = l >> 3, sub = l & 7;
  int cbase = h * 128 + sub * 16;

  float xrv[16], atv[16];
  {
    const uint4* p = (const uint4*)(xr + (long long)node * 1024 + cbase);
    unpack16(p[0], p[1], xrv);
    const float4* pa = (const float4*)(att + cbase);
    float4 a0 = pa[0], a1 = pa[1], a2 = pa[2], a3 = pa[3];
    atv[0] = a0.x; atv[1] = a0.y; atv[2] = a0.z; atv[3] = a0.w;
    atv[4] = a1.x; atv[5] = a1.y; atv[6] = a1.z; atv[7] = a1.w;
    atv[8] = a2.x; atv[9] = a2.y; atv[10] = a2.z; atv[11] = a2.w;
    atv[12] = a3.x; atv[13] = a3.y; atv[14] = a3.z; atv[15] = a3.w;
  }

  float m = -INFINITY, s = 0.f, acc[16] = {};
  int b = rowptr[node], e = rowptr[node + 1];

  auto process = [&](uint4 u0, uint4 u1) {
    float x[16];
    unpack16(u0, u1, x);
    float sc = 0.f;
    #pragma unroll
    for (int j = 0; j < 16; ++j) {
      float t = x[j] + xrv[j];
      t = fmaxf(t, NEG * t);
      sc = fmaf(t, atv[j], sc);
    }
    sc += __shfl_xor(sc, 1); sc += __shfl_xor(sc, 2); sc += __shfl_xor(sc, 4);
    if (sc > m + 8.f) {                  // defer-rescale (T13)
      float scl = __expf(m - sc);
      s *= scl;
      #pragma unroll
      for (int j = 0; j < 16; ++j) acc[j] *= scl;
      m = sc;
    }
    float a = __expf(sc - m);
    s += a;
    #pragma unroll
    for (int j = 0; j < 16; ++j) acc[j] = fmaf(a, x[j], acc[j]);
  };

  int i = b + wsub;
  for (; i + WPN < e; i += 2 * WPN) {
    const uint4* p0 = (const uint4*)(xl + (long long)srcid[i] * 1024 + cbase);
    const uint4* p1 = (const uint4*)(xl + (long long)srcid[i + WPN] * 1024 + cbase);
    uint4 a0 = p0[0], a1 = p0[1], b0 = p1[0], b1 = p1[1];
    process(a0, a1);
    process(b0, b1);
  }
  if (i < e) {
    const uint4* p0 = (const uint4*)(xl + (long long)srcid[i] * 1024 + cbase);
    process(p0[0], p0[1]);
  }

  float val[16];
  if constexpr (WPN == 4) {
    __shared__ float lm[4][8], lss[4][8];
    __shared__ float lacc[4][64][16];
    if (sub == 0) { lm[wsub][h] = m; lss[wsub][h] = s; }
    #pragma unroll
    for (int q = 0; q < 4; ++q) {
      float4 t = {acc[q * 4], acc[q * 4 + 1], acc[q * 4 + 2], acc[q * 4 + 3]};
      *(float4*)&lacc[wsub][l][q * 4] = t;
    }
    __syncthreads();
    if (wsub != 0) return;
    float M2 = fmaxf(fmaxf(lm[0][h], lm[1][h]), fmaxf(lm[2][h], lm[3][h]));
    float S = 0.f;
    #pragma unroll
    for (int j = 0; j < 16; ++j) val[j] = 0.f;
    #pragma unroll
    for (int w2 = 0; w2 < 4; ++w2) {
      float scw = (M2 == -INFINITY) ? 0.f : __expf(lm[w2][h] - M2);
      S = fmaf(scw, lss[w2][h], S);
      #pragma unroll
      for (int j = 0; j < 16; ++j) val[j] = fmaf(scw, lacc[w2][l][j], val[j]);
    }
    float inv = (S > 0.f) ? 1.f / S : 0.f;
    #pragma unroll
    for (int j = 0; j < 16; ++j) val[j] *= inv;
  } else {
    float inv = (s > 0.f) ? 1.f / s : 0.f;
    #pragma unroll
    for (int j = 0; j < 16; ++j) val[j] = acc[j] * inv;
  }
  #pragma unroll
  for (int j = 0; j < 16; ++j) {
    val[j] += __shfl_xor(val[j], 8);
    val[j] += __shfl_xor(val[j], 16);
    val[j] += __shfl_xor(val[j], 32);
  }
  if (l < 8) {
    #pragma unroll
    for (int q = 0; q < 4; ++q) {
      float4 bq = *(const float4*)&bias[sub * 16 + q * 4];
      ushort4 o;
      o.x = f2bf(fmaxf(val[q * 4 + 0] * 0.125f + bq.x, 0.f));
      o.y = f2bf(fmaxf(val[q * 4 + 1] * 0.125f + bq.y, 0.f));
      o.z = f2bf(fmaxf(val[q * 4 + 2] * 0.125f + bq.z, 0.f));
      o.w = f2bf(fmaxf(val[q * 4 + 3] * 0.125f + bq.w, 0.f));
      *(ushort4*)&outb[(long long)node * C2 + sub * 16 + q * 4] = o;
    }
  }
}

// ================= classifier =================
__global__ void k_dot64(const float* __restrict__ xs, const float* __restrict__ xd,
                        const int* __restrict__ ls, const int* __restrict__ ld,
                        float* __restrict__ out, int L) {
  long long t = (long long)blockIdx.x * blockDim.x + threadIdx.x;
  int gw = (int)(t >> 6), lane = (int)(t & 63);
  if (gw >= L) return;
  float v = xs[(long long)ls[gw] * 64 + lane] * xd[(long long)ld[gw] * 64 + lane];
  #pragma unroll
  for (int off = 32; off; off >>= 1) v += __shfl_down(v, off);
  if (lane == 0) out[gw] = v;
}

extern "C" void kernel_launch(void* const* d_in, const int* in_sizes, int n_in,
                              void* d_out, int out_size, void* d_ws, size_t ws_size,
                              hipStream_t stream) {
  const float* x_s = (const float*)d_in[0];
  const float* x_d = (const float*)d_in[1];
  const int* esrc = (const int*)d_in[2];
  const int* edst = (const int*)d_in[3];
  const int* lsrc = (const int*)d_in[4];
  const int* ldst = (const int*)d_in[5];
  const float* W1rel_sd  = (const float*)d_in[6];
  const float* b1_sd     = (const float*)d_in[7];
  const float* W1root_sd = (const float*)d_in[8];
  const float* W1rel_ds  = (const float*)d_in[9];
  const float* b1_ds     = (const float*)d_in[10];
  const float* W1root_ds = (const float*)d_in[11];
  const float *Wl2_sd = (const float*)d_in[12], *bl2_sd = (const float*)d_in[13],
              *Wr2_sd = (const float*)d_in[14], *br2_sd = (const float*)d_in[15],
              *att2_sd = (const float*)d_in[16], *bias2_sd = (const float*)d_in[17];
  const float *Wl2_ds = (const float*)d_in[18], *bl2_ds = (const float*)d_in[19],
              *Wr2_ds = (const float*)d_in[20], *br2_ds = (const float*)d_in[21],
              *att2_ds = (const float*)d_in[22], *bias2_ds = (const float*)d_in[23];
  const float *W3rel_sd = (const float*)d_in[24], *b3_sd = (const float*)d_in[25],
              *W3root_sd = (const float*)d_in[26];
  const float *W3rel_ds = (const float*)d_in[27], *b3_ds = (const float*)d_in[28],
              *W3root_ds = (const float*)d_in[29];
  float* out = (float*)d_out;

  // ---- workspace arena (float units, 256B-aligned) ----
  float* w = (float*)d_ws;
  long long off = 0;
  auto alloc = [&](long long n) { float* p = w + off; off += (n + 63) & ~63LL; return p; };
  unsigned short* xsb   = (unsigned short*)alloc((long long)N_S * 64);   // [N_S,128] bf16
  unsigned short* xdb   = (unsigned short*)alloc((long long)N_D * 32);   // [N_D,64]  bf16
  unsigned short* AGGDb = (unsigned short*)alloc((long long)N_D * 64);   // [N_D,128]
  unsigned short* AGGSb = (unsigned short*)alloc((long long)N_S * 32);   // [N_S,64]
  unsigned short* XS1b  = (unsigned short*)alloc((long long)N_S * 64);   // [N_S,128]
  unsigned short* XD1b  = (unsigned short*)alloc((long long)N_D * 64);   // [N_D,128]
  unsigned short* XLsd  = (unsigned short*)alloc((long long)N_S * 512);  // [N_S,1024]
  unsigned short* XRsd  = (unsigned short*)alloc((long long)N_D * 512);
  unsigned short* XLds  = (unsigned short*)alloc((long long)N_D * 512);
  unsigned short* XRds  = (unsigned short*)alloc((long long)N_S * 512);
  unsigned short* XS2b  = (unsigned short*)alloc((long long)N_S * 64);   // [N_S,128]
  unsigned short* XD2b  = (unsigned short*)alloc((long long)N_D * 64);   // [N_D,128]
  unsigned short* AGD3b = (unsigned short*)alloc((long long)N_D * 64);   // [N_D,128]
  unsigned short* AGS3b = (unsigned short*)alloc((long long)N_S * 64);   // [N_S,128]
  float* XS3 = alloc((long long)N_S * 64);
  float* XD3 = alloc((long long)N_D * 64);
  unsigned short* pk[12];
  const int pksz[12] = {128 * 128, 64 * 128, 64 * 128, 128 * 128,
                        131072, 131072, 131072, 131072,
                        128 * 64, 128 * 64, 128 * 64, 128 * 64};
  for (int i = 0; i < 12; ++i) pk[i] = (unsigned short*)alloc(pksz[i] / 2 + 64);
  int* rowptr_d = (int*)alloc(N_D + 64);
  int* rowptr_s = (int*)alloc(N_S + 64);
  int* cur_all  = (int*)alloc(N_D + N_S + 128);
  int* cur_d = cur_all;
  int* cur_s = cur_all + N_D + 64;
  int* csrc_d = (int*)alloc(E_N);
  int* csrc_s = (int*)alloc(E_N);
  (void)ws_size; (void)in_sizes; (void)n_in; (void)out_size;

  // ================= inputs -> bf16; pack all 12 weight matrices =================
  k_cvt<<<(N_S * 32 + N_D * 16 + 255) / 256, 256, 0, stream>>>(x_s, x_d, xsb, xdb);
  Pk12 pkk = {{{W1rel_sd, pk[0], 128, 128}, {W1root_sd, pk[1], 64, 128},
               {W1rel_ds, pk[2], 64, 128},  {W1root_ds, pk[3], 128, 128},
               {Wl2_sd, pk[4], 128, 1024},  {Wr2_sd, pk[5], 128, 1024},
               {Wl2_ds, pk[6], 128, 1024},  {Wr2_ds, pk[7], 128, 1024},
               {W3rel_sd, pk[8], 128, 64},  {W3root_sd, pk[9], 128, 64},
               {W3rel_ds, pk[10], 128, 64}, {W3root_ds, pk[11], 128, 64}}};
  k_pack<<<dim3(64, 12), 256, 0, stream>>>(pkk);

  // ================= CSR both directions =================
  hipMemsetAsync(cur_all, 0, (size_t)(N_D + N_S + 128) * 4, stream);
  k_hist2<<<(E_N + 255) / 256, 256, 0, stream>>>(esrc, edst, cur_s, cur_d, E_N);
  k_scan2<<<2, 1024, 0, stream>>>(cur_d, rowptr_d, N_D, cur_s, rowptr_s, N_S);
  k_scat2<<<(E_N + 255) / 256, 256, 0, stream>>>(esrc, edst, cur_d, cur_s,
                                                 csrc_d, csrc_s, E_N);

  // ================= layer 1: gather + fused MFMA =================
  k_gather_l1<<<N_D + (N_S + 1) / 2, 128, 0, stream>>>(
      xsb, xdb, rowptr_d, csrc_d, rowptr_s, csrc_s, AGGDb, AGGSb);
  {
    GDs<2> g = {{{AGGDb, pk[0], xdb, pk[1], b1_sd, XD1b, 128, 64, N_D, 128, 1, 1, 0},
                 {AGGSb, pk[2], xsb, pk[3], b1_ds, XS1b, 64, 128, N_S, 128, 1, 1, 32}}};
    k_mfma<2><<<dim3(2, 189), 256, 0, stream>>>(g);
  }

  // ================= layer 2: 4 projections in one MFMA launch + GAT =============
  {
    GDs<4> g = {{{XS1b, pk[4], nullptr, nullptr, bl2_sd, XLsd, 128, 0, N_S, 1024, 0, 1, 0},
                 {XD1b, pk[5], nullptr, nullptr, br2_sd, XRsd, 128, 0, N_D, 1024, 0, 1, 157},
                 {XD1b, pk[6], nullptr, nullptr, bl2_ds, XLds, 128, 0, N_D, 1024, 0, 1, 189},
                 {XS1b, pk[7], nullptr, nullptr, br2_ds, XRds, 128, 0, N_S, 1024, 0, 1, 221}}};
    k_mfma<4><<<dim3(16, 378), 256, 0, stream>>>(g);
  }
  k_gatv2<4><<<N_D, 256, 0, stream>>>(XLsd, XRsd, rowptr_d, csrc_d,
                                      att2_sd, bias2_sd, XD2b, N_D);
  k_gatv2<1><<<(N_S + 3) / 4, 256, 0, stream>>>(XLds, XRds, rowptr_s, csrc_s,
                                                att2_ds, bias2_ds, XS2b, N_S);

  // ================= layer 3: gather + fused MFMA (fp32 out) =================
  k_gather_l3<<<N_D + N_S, 128, 0, stream>>>(
      XS2b, XD2b, rowptr_d, csrc_d, rowptr_s, csrc_s, AGD3b, AGS3b);
  {
    GDs<2> g = {{{AGD3b, pk[8], XD2b, pk[9], b3_sd, XD3, 128, 128, N_D, 64, 0, 0, 0},
                 {AGS3b, pk[10], XS2b, pk[11], b3_ds, XS3, 128, 128, N_S, 64, 0, 0, 32}}};
    k_mfma<2><<<dim3(1, 189), 256, 0, stream>>>(g);
  }

  // ================= classifier =================
  long long tw = (long long)L_N * 64;
  k_dot64<<<(int)((tw + 255) / 256), 256, 0, stream>>>(XS3, XD3, lsrc, ldst, out, L_N);
}

// Round 6
// 210.827 us; speedup vs baseline: 9.7709x; 1.0307x over previous
//
#include <hip/hip_runtime.h>
#include <math.h>

#define HH 8
#define C2 128
#define NEG 0.2f

static const int N_S = 10000, N_D = 2000, E_N = 100000, L_N = 50000;

using short8 = __attribute__((ext_vector_type(8))) short;
using f32x4  = __attribute__((ext_vector_type(4))) float;

__device__ inline unsigned short f2bf(float f) {
  unsigned u = __float_as_uint(f);
  u += 0x7fff + ((u >> 16) & 1);          // round-to-nearest-even
  return (unsigned short)(u >> 16);
}
__device__ inline float bf2f(unsigned short u) {
  return __uint_as_float((unsigned)u << 16);
}
__device__ inline void unpack16(uint4 u0, uint4 u1, float* x) {
  x[0]  = __uint_as_float(u0.x << 16); x[1]  = __uint_as_float(u0.x & 0xffff0000u);
  x[2]  = __uint_as_float(u0.y << 16); x[3]  = __uint_as_float(u0.y & 0xffff0000u);
  x[4]  = __uint_as_float(u0.z << 16); x[5]  = __uint_as_float(u0.z & 0xffff0000u);
  x[6]  = __uint_as_float(u0.w << 16); x[7]  = __uint_as_float(u0.w & 0xffff0000u);
  x[8]  = __uint_as_float(u1.x << 16); x[9]  = __uint_as_float(u1.x & 0xffff0000u);
  x[10] = __uint_as_float(u1.y << 16); x[11] = __uint_as_float(u1.y & 0xffff0000u);
  x[12] = __uint_as_float(u1.z << 16); x[13] = __uint_as_float(u1.z & 0xffff0000u);
  x[14] = __uint_as_float(u1.w << 16); x[15] = __uint_as_float(u1.w & 0xffff0000u);
}

// ================= CSR build (fused both directions) =================
__global__ void k_hist2(const int* __restrict__ es, const int* __restrict__ ed,
                        int* __restrict__ deg_s, int* __restrict__ deg_d, int E) {
  int e = blockIdx.x * 256 + threadIdx.x;
  if (e < E) {
    atomicAdd(&deg_d[ed[e]], 1);
    atomicAdd(&deg_s[es[e]], 1);
  }
}

__global__ __launch_bounds__(1024) void k_scan2(int* c0, int* r0, int n0,
                                                int* c1, int* r1, int n1) {
  int* cur = blockIdx.x ? c1 : c0;
  int* rp  = blockIdx.x ? r1 : r0;
  int N    = blockIdx.x ? n1 : n0;
  __shared__ int wsum[16];
  __shared__ int carry;
  if (threadIdx.x == 0) carry = 0;
  __syncthreads();
  int lane = threadIdx.x & 63, wid = threadIdx.x >> 6;
  for (int base = 0; base < N; base += 1024) {
    int i = base + threadIdx.x;
    int v = (i < N) ? cur[i] : 0;
    int x = v;
    #pragma unroll
    for (int dd = 1; dd < 64; dd <<= 1) {
      int t = __shfl_up(x, dd);
      if (lane >= dd) x += t;
    }
    if (lane == 63) wsum[wid] = x;
    __syncthreads();
    int woff = 0;
    for (int ww = 0; ww < wid; ++ww) woff += wsum[ww];
    int cl = carry;
    int excl = cl + woff + x - v;
    if (i < N) { rp[i] = excl; cur[i] = excl; }
    __syncthreads();
    if (threadIdx.x == 0) {
      int t = 0;
      #pragma unroll
      for (int ww = 0; ww < 16; ++ww) t += wsum[ww];
      if (base + 1024 >= N) rp[N] = carry + t;
      carry += t;
    }
    __syncthreads();
  }
}

__global__ void k_scat2(const int* __restrict__ es, const int* __restrict__ ed,
                        int* __restrict__ cur_d, int* __restrict__ cur_s,
                        int* __restrict__ csrc_d, int* __restrict__ csrc_s, int E) {
  int e = blockIdx.x * 256 + threadIdx.x;
  if (e >= E) return;
  int s = es[e], d = ed[e];
  csrc_d[atomicAdd(&cur_d[d], 1)] = s;
  csrc_s[atomicAdd(&cur_s[s], 1)] = d;
}

// ================= input fp32 -> bf16 =================
__global__ void k_cvt(const float* __restrict__ xs, const float* __restrict__ xd,
                      unsigned short* __restrict__ xsb, unsigned short* __restrict__ xdb) {
  int i = blockIdx.x * 256 + threadIdx.x;
  const int ns4 = N_S * 128 / 4, nd4 = N_D * 64 / 4;
  if (i < ns4) {
    float4 v = ((const float4*)xs)[i];
    ushort4 o = {f2bf(v.x), f2bf(v.y), f2bf(v.z), f2bf(v.w)};
    ((ushort4*)xsb)[i] = o;
  } else if (i < ns4 + nd4) {
    int j = i - ns4;
    float4 v = ((const float4*)xd)[j];
    ushort4 o = {f2bf(v.x), f2bf(v.y), f2bf(v.z), f2bf(v.w)};
    ((ushort4*)xdb)[j] = o;
  }
}

// ================= pack fp32 W[K,M] -> bf16 MFMA B-fragments =================
struct PkD { const float* W; unsigned short* P; int K, M; };
struct Pk12 { PkD d[12]; };
__global__ void k_pack(Pk12 g) {
  PkD d = g.d[blockIdx.y];
  int total = d.K * d.M;
  int mt = d.M >> 4;
  for (int tid = blockIdx.x * 256 + threadIdx.x; tid < total; tid += gridDim.x * 256) {
    int r = tid & 7, l = (tid >> 3) & 63;
    int rest = tid >> 9;
    int ct = rest % mt, kt = rest / mt;
    int k = kt * 32 + (l >> 4) * 8 + r;
    int col = ct * 16 + (l & 15);
    d.P[tid] = f2bf(d.W[k * d.M + col]);
  }
}

// ================= CSR gather-sum layer 1 ==============
__global__ __launch_bounds__(128) void k_gather_l1(
    const unsigned short* __restrict__ xsb, const unsigned short* __restrict__ xdb,
    const int* __restrict__ rpd, const int* __restrict__ csd,
    const int* __restrict__ rps, const int* __restrict__ css,
    unsigned short* __restrict__ aggd, unsigned short* __restrict__ aggs) {
  if (blockIdx.x < N_D) {
    int n = blockIdx.x, c = threadIdx.x;
    int b = rpd[n], e = rpd[n + 1];
    float acc = 0.f;
    int i = b;
    for (; i + 1 < e; i += 2)
      acc += bf2f(xsb[(long long)csd[i] * 128 + c]) +
             bf2f(xsb[(long long)csd[i + 1] * 128 + c]);
    if (i < e) acc += bf2f(xsb[(long long)csd[i] * 128 + c]);
    aggd[(long long)n * 128 + c] = f2bf(acc);
  } else {
    int n = (blockIdx.x - N_D) * 2 + (threadIdx.x >> 6);
    int c = threadIdx.x & 63;
    if (n >= N_S) return;
    int b = rps[n], e = rps[n + 1];
    float acc = 0.f;
    int i = b;
    for (; i + 1 < e; i += 2)
      acc += bf2f(xdb[(long long)css[i] * 64 + c]) +
             bf2f(xdb[(long long)css[i + 1] * 64 + c]);
    if (i < e) acc += bf2f(xdb[(long long)css[i] * 64 + c]);
    aggs[(long long)n * 64 + c] = f2bf(acc);
  }
}

// ================= CSR gather-sum layer 3 ==============
__global__ __launch_bounds__(128) void k_gather_l3(
    const unsigned short* __restrict__ xs2b, const unsigned short* __restrict__ xd2b,
    const int* __restrict__ rpd, const int* __restrict__ csd,
    const int* __restrict__ rps, const int* __restrict__ css,
    unsigned short* __restrict__ aggd, unsigned short* __restrict__ aggs) {
  int c = threadIdx.x;
  if (blockIdx.x < N_D) {
    int n = blockIdx.x;
    int b = rpd[n], e = rpd[n + 1];
    float acc = 0.f;
    int i = b;
    for (; i + 1 < e; i += 2)
      acc += bf2f(xs2b[(long long)csd[i] * 128 + c]) +
             bf2f(xs2b[(long long)csd[i + 1] * 128 + c]);
    if (i < e) acc += bf2f(xs2b[(long long)csd[i] * 128 + c]);
    aggd[(long long)n * 128 + c] = f2bf(acc);
  } else {
    int n = blockIdx.x - N_D;
    int b = rps[n], e = rps[n + 1];
    float acc = 0.f;
    int i = b;
    for (; i + 1 < e; i += 2)
      acc += bf2f(xd2b[(long long)css[i] * 128 + c]) +
             bf2f(xd2b[(long long)css[i + 1] * 128 + c]);
    if (i < e) acc += bf2f(xd2b[(long long)css[i] * 128 + c]);
    aggs[(long long)n * 128 + c] = f2bf(acc);
  }
}

// ================= generic fused MFMA GEMM =================
struct GD {
  const unsigned short *A0, *P0, *A1, *P1;
  const float* bias;
  void* out;
  int K0, K1, N, M, relu, outbf, y0;
};
template<int ND> struct GDs { GD d[ND]; };

template<int ND>
__global__ __launch_bounds__(256) void k_mfma(GDs<ND> g) {
  int by = blockIdx.y;
  int di = 0;
  #pragma unroll
  for (int i = 1; i < ND; ++i) if (by >= g.d[i].y0) di = i;
  GD d = g.d[di];
  int ytile = by - d.y0;
  int c0 = blockIdx.x * 64;
  if (c0 >= d.M) return;
  int w = threadIdx.x >> 6, l = threadIdx.x & 63;
  int r0 = ytile * 64 + w * 16;
  if (r0 >= d.N) return;
  int lg = l >> 4, lo = l & 15;
  f32x4 acc[4] = {};
  int arow = r0 + lo; arow = (arow < d.N) ? arow : (d.N - 1);
  int mt = d.M >> 4;
  int ct0 = c0 >> 4;
  const unsigned short* a0 = d.A0 + (long long)arow * d.K0 + lg * 8;
  for (int kt = 0; kt < (d.K0 >> 5); ++kt) {
    short8 a = *(const short8*)(a0 + kt * 32);
    #pragma unroll
    for (int ct = 0; ct < 4; ++ct) {
      short8 b = *(const short8*)(d.P0 + ((long long)(kt * mt + ct0 + ct) * 64 + l) * 8);
      acc[ct] = __builtin_amdgcn_mfma_f32_16x16x32_bf16(a, b, acc[ct], 0, 0, 0);
    }
  }
  if (d.K1) {
    const unsigned short* a1 = d.A1 + (long long)arow * d.K1 + lg * 8;
    for (int kt = 0; kt < (d.K1 >> 5); ++kt) {
      short8 a = *(const short8*)(a1 + kt * 32);
      #pragma unroll
      for (int ct = 0; ct < 4; ++ct) {
        short8 b = *(const short8*)(d.P1 + ((long long)(kt * mt + ct0 + ct) * 64 + l) * 8);
        acc[ct] = __builtin_amdgcn_mfma_f32_16x16x32_bf16(a, b, acc[ct], 0, 0, 0);
      }
    }
  }
  #pragma unroll
  for (int ct = 0; ct < 4; ++ct) {
    int col = c0 + ct * 16 + lo;
    float bv = d.bias[col];
    #pragma unroll
    for (int r = 0; r < 4; ++r) {
      int grow = r0 + lg * 4 + r;
      if (grow < d.N) {
        float v = acc[ct][r] + bv;
        if (d.relu) v = fmaxf(v, 0.f);
        if (d.outbf)
          ((unsigned short*)d.out)[(long long)grow * d.M + col] = f2bf(v);
        else
          ((float*)d.out)[(long long)grow * d.M + col] = v;
      }
    }
  }
}

// ================= GATv2 per-node body with 4-edge software pipeline ============
template<int WPN>
__device__ __forceinline__ void gat_node(
    const unsigned short* __restrict__ xl, const unsigned short* __restrict__ xr,
    const int* __restrict__ rowptr, const int* __restrict__ srcid,
    const float* __restrict__ att, const float* __restrict__ bias,
    unsigned short* __restrict__ outb, int node, int wsub, int l,
    float (*lm)[8], float (*lss)[8], float (*lacc)[64][16]) {
  int h = l >> 3, sub = l & 7;
  int cbase = h * 128 + sub * 16;

  float xrv[16], atv[16];
  {
    const uint4* p = (const uint4*)(xr + (long long)node * 1024 + cbase);
    unpack16(p[0], p[1], xrv);
    const float4* pa = (const float4*)(att + cbase);
    float4 a0 = pa[0], a1 = pa[1], a2 = pa[2], a3 = pa[3];
    atv[0] = a0.x; atv[1] = a0.y; atv[2] = a0.z; atv[3] = a0.w;
    atv[4] = a1.x; atv[5] = a1.y; atv[6] = a1.z; atv[7] = a1.w;
    atv[8] = a2.x; atv[9] = a2.y; atv[10] = a2.z; atv[11] = a2.w;
    atv[12] = a3.x; atv[13] = a3.y; atv[14] = a3.z; atv[15] = a3.w;
  }

  float m = -INFINITY, s = 0.f, acc[16] = {};
  int b = rowptr[node], e = rowptr[node + 1];

  auto process = [&](uint4 u0, uint4 u1) {
    float x[16];
    unpack16(u0, u1, x);
    float sc = 0.f;
    #pragma unroll
    for (int j = 0; j < 16; ++j) {
      float t = x[j] + xrv[j];
      t = fmaxf(t, NEG * t);
      sc = fmaf(t, atv[j], sc);
    }
    sc += __shfl_xor(sc, 1); sc += __shfl_xor(sc, 2); sc += __shfl_xor(sc, 4);
    if (sc > m + 8.f) {                  // defer-rescale (T13)
      float scl = __expf(m - sc);
      s *= scl;
      #pragma unroll
      for (int j = 0; j < 16; ++j) acc[j] *= scl;
      m = sc;
    }
    float a = __expf(sc - m);
    s += a;
    #pragma unroll
    for (int j = 0; j < 16; ++j) acc[j] = fmaf(a, x[j], acc[j]);
  };

  // 2-deep (4-edge window) software pipeline: issue loads for i+2,i+3 while
  // computing i,i+1 (T14 issue-early / use-late)
  int i = b + wsub;
  uint4 c0, c1, d0, d1;
  bool hc = (i < e), hd = (i + WPN < e);
  if (hc) { const uint4* p = (const uint4*)(xl + (long long)srcid[i] * 1024 + cbase); c0 = p[0]; c1 = p[1]; }
  if (hd) { const uint4* p = (const uint4*)(xl + (long long)srcid[i + WPN] * 1024 + cbase); d0 = p[0]; d1 = p[1]; }
  while (hc) {
    int inx = i + 2 * WPN;
    uint4 n0, n1, n2, n3;
    bool h0 = (inx < e), h1 = (inx + WPN < e);
    if (h0) { const uint4* p = (const uint4*)(xl + (long long)srcid[inx] * 1024 + cbase); n0 = p[0]; n1 = p[1]; }
    if (h1) { const uint4* p = (const uint4*)(xl + (long long)srcid[inx + WPN] * 1024 + cbase); n2 = p[0]; n3 = p[1]; }
    process(c0, c1);
    if (hd) process(d0, d1);
    c0 = n0; c1 = n1; d0 = n2; d1 = n3;
    hc = h0; hd = h1;
    i = inx;
  }

  float val[16];
  if constexpr (WPN == 4) {
    if (sub == 0) { lm[wsub][h] = m; lss[wsub][h] = s; }
    #pragma unroll
    for (int q = 0; q < 4; ++q) {
      float4 t = {acc[q * 4], acc[q * 4 + 1], acc[q * 4 + 2], acc[q * 4 + 3]};
      *(float4*)&lacc[wsub][l][q * 4] = t;
    }
    __syncthreads();
    if (wsub != 0) return;
    float M2 = fmaxf(fmaxf(lm[0][h], lm[1][h]), fmaxf(lm[2][h], lm[3][h]));
    float S = 0.f;
    #pragma unroll
    for (int j = 0; j < 16; ++j) val[j] = 0.f;
    #pragma unroll
    for (int w2 = 0; w2 < 4; ++w2) {
      float scw = (M2 == -INFINITY) ? 0.f : __expf(lm[w2][h] - M2);
      S = fmaf(scw, lss[w2][h], S);
      #pragma unroll
      for (int j = 0; j < 16; ++j) val[j] = fmaf(scw, lacc[w2][l][j], val[j]);
    }
    float inv = (S > 0.f) ? 1.f / S : 0.f;
    #pragma unroll
    for (int j = 0; j < 16; ++j) val[j] *= inv;
  } else {
    float inv = (s > 0.f) ? 1.f / s : 0.f;
    #pragma unroll
    for (int j = 0; j < 16; ++j) val[j] = acc[j] * inv;
  }
  #pragma unroll
  for (int j = 0; j < 16; ++j) {
    val[j] += __shfl_xor(val[j], 8);
    val[j] += __shfl_xor(val[j], 16);
    val[j] += __shfl_xor(val[j], 32);
  }
  if (l < 8) {
    #pragma unroll
    for (int q = 0; q < 4; ++q) {
      float4 bq = *(const float4*)&bias[sub * 16 + q * 4];
      ushort4 o;
      o.x = f2bf(fmaxf(val[q * 4 + 0] * 0.125f + bq.x, 0.f));
      o.y = f2bf(fmaxf(val[q * 4 + 1] * 0.125f + bq.y, 0.f));
      o.z = f2bf(fmaxf(val[q * 4 + 2] * 0.125f + bq.z, 0.f));
      o.w = f2bf(fmaxf(val[q * 4 + 3] * 0.125f + bq.w, 0.f));
      *(ushort4*)&outb[(long long)node * C2 + sub * 16 + q * 4] = o;
    }
  }
}

// ================= merged GAT launch: sd blocks then ds blocks =================
__global__ __launch_bounds__(256) void k_gat_both(
    const unsigned short* __restrict__ XLsd, const unsigned short* __restrict__ XRsd,
    const int* __restrict__ rpd, const int* __restrict__ csd,
    const float* __restrict__ att_sd, const float* __restrict__ bias_sd,
    unsigned short* __restrict__ XD2b,
    const unsigned short* __restrict__ XLds, const unsigned short* __restrict__ XRds,
    const int* __restrict__ rps, const int* __restrict__ css,
    const float* __restrict__ att_ds, const float* __restrict__ bias_ds,
    unsigned short* __restrict__ XS2b) {
  __shared__ float lm[4][8], lss[4][8];
  __shared__ float lacc[4][64][16];
  int widx = threadIdx.x >> 6, l = threadIdx.x & 63;
  if (blockIdx.x < (unsigned)N_D) {
    gat_node<4>(XLsd, XRsd, rpd, csd, att_sd, bias_sd, XD2b,
                blockIdx.x, widx, l, lm, lss, lacc);
  } else {
    int node = (blockIdx.x - N_D) * 4 + widx;
    if (node < N_S)
      gat_node<1>(XLds, XRds, rps, css, att_ds, bias_ds, XS2b,
                  node, 0, l, lm, lss, lacc);
  }
}

// ================= classifier: 4 edges/wave, float4 loads =================
__global__ void k_dot64(const float* __restrict__ xs, const float* __restrict__ xd,
                        const int* __restrict__ ls, const int* __restrict__ ld,
                        float* __restrict__ out, int L) {
  long long t = (long long)blockIdx.x * blockDim.x + threadIdx.x;
  int wave = (int)(t >> 6), lane = (int)(t & 63);
  int q = lane >> 4, sub = lane & 15;
  int eidx = wave * 4 + q;
  if (eidx >= L) return;
  const float4* a = (const float4*)(xs + (long long)ls[eidx] * 64);
  const float4* b = (const float4*)(xd + (long long)ld[eidx] * 64);
  float4 va = a[sub], vb = b[sub];
  float v = va.x * vb.x + va.y * vb.y + va.z * vb.z + va.w * vb.w;
  v += __shfl_xor(v, 1); v += __shfl_xor(v, 2);
  v += __shfl_xor(v, 4); v += __shfl_xor(v, 8);
  if (sub == 0) out[eidx] = v;
}

extern "C" void kernel_launch(void* const* d_in, const int* in_sizes, int n_in,
                              void* d_out, int out_size, void* d_ws, size_t ws_size,
                              hipStream_t stream) {
  const float* x_s = (const float*)d_in[0];
  const float* x_d = (const float*)d_in[1];
  const int* esrc = (const int*)d_in[2];
  const int* edst = (const int*)d_in[3];
  const int* lsrc = (const int*)d_in[4];
  const int* ldst = (const int*)d_in[5];
  const float* W1rel_sd  = (const float*)d_in[6];
  const float* b1_sd     = (const float*)d_in[7];
  const float* W1root_sd = (const float*)d_in[8];
  const float* W1rel_ds  = (const float*)d_in[9];
  const float* b1_ds     = (const float*)d_in[10];
  const float* W1root_ds = (const float*)d_in[11];
  const float *Wl2_sd = (const float*)d_in[12], *bl2_sd = (const float*)d_in[13],
              *Wr2_sd = (const float*)d_in[14], *br2_sd = (const float*)d_in[15],
              *att2_sd = (const float*)d_in[16], *bias2_sd = (const float*)d_in[17];
  const float *Wl2_ds = (const float*)d_in[18], *bl2_ds = (const float*)d_in[19],
              *Wr2_ds = (const float*)d_in[20], *br2_ds = (const float*)d_in[21],
              *att2_ds = (const float*)d_in[22], *bias2_ds = (const float*)d_in[23];
  const float *W3rel_sd = (const float*)d_in[24], *b3_sd = (const float*)d_in[25],
              *W3root_sd = (const float*)d_in[26];
  const float *W3rel_ds = (const float*)d_in[27], *b3_ds = (const float*)d_in[28],
              *W3root_ds = (const float*)d_in[29];
  float* out = (float*)d_out;

  // ---- workspace arena ----
  float* w = (float*)d_ws;
  long long off = 0;
  auto alloc = [&](long long n) { float* p = w + off; off += (n + 63) & ~63LL; return p; };
  unsigned short* xsb   = (unsigned short*)alloc((long long)N_S * 64);
  unsigned short* xdb   = (unsigned short*)alloc((long long)N_D * 32);
  unsigned short* AGGDb = (unsigned short*)alloc((long long)N_D * 64);
  unsigned short* AGGSb = (unsigned short*)alloc((long long)N_S * 32);
  unsigned short* XS1b  = (unsigned short*)alloc((long long)N_S * 64);
  unsigned short* XD1b  = (unsigned short*)alloc((long long)N_D * 64);
  unsigned short* XLsd  = (unsigned short*)alloc((long long)N_S * 512);
  unsigned short* XRsd  = (unsigned short*)alloc((long long)N_D * 512);
  unsigned short* XLds  = (unsigned short*)alloc((long long)N_D * 512);
  unsigned short* XRds  = (unsigned short*)alloc((long long)N_S * 512);
  unsigned short* XS2b  = (unsigned short*)alloc((long long)N_S * 64);
  unsigned short* XD2b  = (unsigned short*)alloc((long long)N_D * 64);
  unsigned short* AGD3b = (unsigned short*)alloc((long long)N_D * 64);
  unsigned short* AGS3b = (unsigned short*)alloc((long long)N_S * 64);
  float* XS3 = alloc((long long)N_S * 64);
  float* XD3 = alloc((long long)N_D * 64);
  unsigned short* pk[12];
  const int pksz[12] = {128 * 128, 64 * 128, 64 * 128, 128 * 128,
                        131072, 131072, 131072, 131072,
                        128 * 64, 128 * 64, 128 * 64, 128 * 64};
  for (int i = 0; i < 12; ++i) pk[i] = (unsigned short*)alloc(pksz[i] / 2 + 64);
  int* rowptr_d = (int*)alloc(N_D + 64);
  int* rowptr_s = (int*)alloc(N_S + 64);
  int* cur_all  = (int*)alloc(N_D + N_S + 128);
  int* cur_d = cur_all;
  int* cur_s = cur_all + N_D + 64;
  int* csrc_d = (int*)alloc(E_N);
  int* csrc_s = (int*)alloc(E_N);
  (void)ws_size; (void)in_sizes; (void)n_in; (void)out_size;

  // ================= inputs -> bf16; pack weights =================
  k_cvt<<<(N_S * 32 + N_D * 16 + 255) / 256, 256, 0, stream>>>(x_s, x_d, xsb, xdb);
  Pk12 pkk = {{{W1rel_sd, pk[0], 128, 128}, {W1root_sd, pk[1], 64, 128},
               {W1rel_ds, pk[2], 64, 128},  {W1root_ds, pk[3], 128, 128},
               {Wl2_sd, pk[4], 128, 1024},  {Wr2_sd, pk[5], 128, 1024},
               {Wl2_ds, pk[6], 128, 1024},  {Wr2_ds, pk[7], 128, 1024},
               {W3rel_sd, pk[8], 128, 64},  {W3root_sd, pk[9], 128, 64},
               {W3rel_ds, pk[10], 128, 64}, {W3root_ds, pk[11], 128, 64}}};
  k_pack<<<dim3(64, 12), 256, 0, stream>>>(pkk);

  // ================= CSR both directions =================
  hipMemsetAsync(cur_all, 0, (size_t)(N_D + N_S + 128) * 4, stream);
  k_hist2<<<(E_N + 255) / 256, 256, 0, stream>>>(esrc, edst, cur_s, cur_d, E_N);
  k_scan2<<<2, 1024, 0, stream>>>(cur_d, rowptr_d, N_D, cur_s, rowptr_s, N_S);
  k_scat2<<<(E_N + 255) / 256, 256, 0, stream>>>(esrc, edst, cur_d, cur_s,
                                                 csrc_d, csrc_s, E_N);

  // ================= layer 1 =================
  k_gather_l1<<<N_D + (N_S + 1) / 2, 128, 0, stream>>>(
      xsb, xdb, rowptr_d, csrc_d, rowptr_s, csrc_s, AGGDb, AGGSb);
  {
    GDs<2> g = {{{AGGDb, pk[0], xdb, pk[1], b1_sd, XD1b, 128, 64, N_D, 128, 1, 1, 0},
                 {AGGSb, pk[2], xsb, pk[3], b1_ds, XS1b, 64, 128, N_S, 128, 1, 1, 32}}};
    k_mfma<2><<<dim3(2, 189), 256, 0, stream>>>(g);
  }

  // ================= layer 2 =================
  {
    GDs<4> g = {{{XS1b, pk[4], nullptr, nullptr, bl2_sd, XLsd, 128, 0, N_S, 1024, 0, 1, 0},
                 {XD1b, pk[5], nullptr, nullptr, br2_sd, XRsd, 128, 0, N_D, 1024, 0, 1, 157},
                 {XD1b, pk[6], nullptr, nullptr, bl2_ds, XLds, 128, 0, N_D, 1024, 0, 1, 189},
                 {XS1b, pk[7], nullptr, nullptr, br2_ds, XRds, 128, 0, N_S, 1024, 0, 1, 221}}};
    k_mfma<4><<<dim3(16, 378), 256, 0, stream>>>(g);
  }
  k_gat_both<<<N_D + (N_S + 3) / 4, 256, 0, stream>>>(
      XLsd, XRsd, rowptr_d, csrc_d, att2_sd, bias2_sd, XD2b,
      XLds, XRds, rowptr_s, csrc_s, att2_ds, bias2_ds, XS2b);

  // ================= layer 3 =================
  k_gather_l3<<<N_D + N_S, 128, 0, stream>>>(
      XS2b, XD2b, rowptr_d, csrc_d, rowptr_s, csrc_s, AGD3b, AGS3b);
  {
    GDs<2> g = {{{AGD3b, pk[8], XD2b, pk[9], b3_sd, XD3, 128, 128, N_D, 64, 0, 0, 0},
                 {AGS3b, pk[10], XS2b, pk[11], b3_ds, XS3, 128, 128, N_S, 64, 0, 0, 32}}};
    k_mfma<2><<<dim3(1, 189), 256, 0, stream>>>(g);
  }

  // ================= classifier =================
  k_dot64<<<(L_N * 16 + 255) / 256, 256, 0, stream>>>(XS3, XD3, lsrc, ldst, out, L_N);
}

// Round 7
// 199.582 us; speedup vs baseline: 10.3213x; 1.0563x over previous
//
#include <hip/hip_runtime.h>
#include <math.h>

#define NEG 0.2f
static const int N_S = 10000, N_D = 2000, E_N = 100000, L_N = 50000;

using short8 = __attribute__((ext_vector_type(8))) short;
using f32x4  = __attribute__((ext_vector_type(4))) float;
typedef _Float16 h2 __attribute__((ext_vector_type(2)));

union U8h { uint4 u[2]; h2 h[8]; unsigned w[8]; };

__device__ inline unsigned short f2bf(float f) {
  unsigned u = __float_as_uint(f);
  u += 0x7fff + ((u >> 16) & 1);
  return (unsigned short)(u >> 16);
}
__device__ inline float bf2f(unsigned short u) {
  return __uint_as_float((unsigned)u << 16);
}
__device__ inline unsigned short f2h(float f) {
  _Float16 h = (_Float16)f;
  unsigned short r;
  __builtin_memcpy(&r, &h, 2);
  return r;
}

// ================= fused prep: hist + cvt-bf16 + weight-pack + att-f16 ==========
struct PkD { const float* W; unsigned short* P; int K, M; };
struct Pk12 { PkD d[12]; };
struct PrepArgs {
  const int *es, *ed;
  int *deg_s, *deg_d;
  const float *xs, *xd;
  unsigned short *xsb, *xdb;
  const float *att_sd, *att_ds;
  unsigned short *att16;          // [2048] f16
};
// blocks: [0,391) hist | [391,1766) cvt | [1766,2534) pack | [2534,2542) att
__global__ void k_prep(PrepArgs a, Pk12 g) {
  int bid = blockIdx.x, t = threadIdx.x;
  if (bid < 391) {
    int e = bid * 256 + t;
    if (e < E_N) {
      atomicAdd(&a.deg_d[a.ed[e]], 1);
      atomicAdd(&a.deg_s[a.es[e]], 1);
    }
  } else if (bid < 391 + 1375) {
    int i = (bid - 391) * 256 + t;      // < 352000
    const int ns4 = N_S * 32;           // 320000
    if (i < ns4) {
      float4 v = ((const float4*)a.xs)[i];
      ushort4 o = {f2bf(v.x), f2bf(v.y), f2bf(v.z), f2bf(v.w)};
      ((ushort4*)a.xsb)[i] = o;
    } else {
      int j = i - ns4;
      float4 v = ((const float4*)a.xd)[j];
      ushort4 o = {f2bf(v.x), f2bf(v.y), f2bf(v.z), f2bf(v.w)};
      ((ushort4*)a.xdb)[j] = o;
    }
  } else if (bid < 391 + 1375 + 768) {
    int sub = bid - 391 - 1375;
    PkD d = g.d[sub >> 6];
    int total = d.K * d.M, mt = d.M >> 4;
    for (int tid = (sub & 63) * 256 + t; tid < total; tid += 64 * 256) {
      int r = tid & 7, l = (tid >> 3) & 63, rest = tid >> 9;
      int ct = rest % mt, kt = rest / mt;
      d.P[tid] = f2bf(d.W[(kt * 32 + (l >> 4) * 8 + r) * d.M + ct * 16 + (l & 15)]);
    }
  } else {
    int i = (bid - 391 - 1375 - 768) * 256 + t;   // < 2048
    float v = (i < 1024) ? a.att_sd[i] : a.att_ds[i - 1024];
    a.att16[i] = f2h(v);
  }
}

// ================= CSR scan (2 blocks) + scatter =================
__global__ __launch_bounds__(1024) void k_scan2(int* c0, int* r0, int n0,
                                                int* c1, int* r1, int n1) {
  int* cur = blockIdx.x ? c1 : c0;
  int* rp  = blockIdx.x ? r1 : r0;
  int N    = blockIdx.x ? n1 : n0;
  __shared__ int wsum[16];
  __shared__ int carry;
  if (threadIdx.x == 0) carry = 0;
  __syncthreads();
  int lane = threadIdx.x & 63, wid = threadIdx.x >> 6;
  for (int base = 0; base < N; base += 1024) {
    int i = base + threadIdx.x;
    int v = (i < N) ? cur[i] : 0;
    int x = v;
    #pragma unroll
    for (int dd = 1; dd < 64; dd <<= 1) {
      int t = __shfl_up(x, dd);
      if (lane >= dd) x += t;
    }
    if (lane == 63) wsum[wid] = x;
    __syncthreads();
    int woff = 0;
    for (int ww = 0; ww < wid; ++ww) woff += wsum[ww];
    int excl = carry + woff + x - v;
    if (i < N) { rp[i] = excl; cur[i] = excl; }
    __syncthreads();
    if (threadIdx.x == 0) {
      int t = 0;
      #pragma unroll
      for (int ww = 0; ww < 16; ++ww) t += wsum[ww];
      if (base + 1024 >= N) rp[N] = carry + t;
      carry += t;
    }
    __syncthreads();
  }
}

__global__ void k_scat2(const int* __restrict__ es, const int* __restrict__ ed,
                        int* __restrict__ cur_d, int* __restrict__ cur_s,
                        int* __restrict__ csrc_d, int* __restrict__ csrc_s, int E) {
  int e = blockIdx.x * 256 + threadIdx.x;
  if (e >= E) return;
  int s = es[e], d = ed[e];
  csrc_d[atomicAdd(&cur_d[d], 1)] = s;
  csrc_s[atomicAdd(&cur_s[s], 1)] = d;
}

// ================= vectorized CSR gather (wave per node, 2 edges in flight) =====
__device__ __forceinline__ void gath128(const unsigned short* __restrict__ x,
                                        const int* __restrict__ rp, const int* __restrict__ cs,
                                        unsigned short* __restrict__ out,
                                        int n, int half, int cl) {
  int b = rp[n], e = rp[n + 1];
  float a0 = 0.f, a1 = 0.f, a2 = 0.f, a3 = 0.f;
  int i = b + half;
  for (; i + 2 < e; i += 4) {
    uint2 v0 = *(const uint2*)(x + (long long)cs[i] * 128 + cl * 4);
    uint2 v1 = *(const uint2*)(x + (long long)cs[i + 2] * 128 + cl * 4);
    a0 += bf2f((unsigned short)(v0.x & 0xffff)) + bf2f((unsigned short)(v1.x & 0xffff));
    a1 += bf2f((unsigned short)(v0.x >> 16))    + bf2f((unsigned short)(v1.x >> 16));
    a2 += bf2f((unsigned short)(v0.y & 0xffff)) + bf2f((unsigned short)(v1.y & 0xffff));
    a3 += bf2f((unsigned short)(v0.y >> 16))    + bf2f((unsigned short)(v1.y >> 16));
  }
  for (; i < e; i += 2) {
    uint2 v0 = *(const uint2*)(x + (long long)cs[i] * 128 + cl * 4);
    a0 += bf2f((unsigned short)(v0.x & 0xffff));
    a1 += bf2f((unsigned short)(v0.x >> 16));
    a2 += bf2f((unsigned short)(v0.y & 0xffff));
    a3 += bf2f((unsigned short)(v0.y >> 16));
  }
  a0 += __shfl_xor(a0, 32); a1 += __shfl_xor(a1, 32);
  a2 += __shfl_xor(a2, 32); a3 += __shfl_xor(a3, 32);
  if (!half) {
    ushort4 o = {f2bf(a0), f2bf(a1), f2bf(a2), f2bf(a3)};
    *(ushort4*)&out[(long long)n * 128 + cl * 4] = o;
  }
}

__global__ __launch_bounds__(256) void k_gather1(
    const unsigned short* __restrict__ xsb, const unsigned short* __restrict__ xdb,
    const int* __restrict__ rpd, const int* __restrict__ csd,
    const int* __restrict__ rps, const int* __restrict__ css,
    unsigned short* __restrict__ aggd, unsigned short* __restrict__ aggs) {
  int wv = threadIdx.x >> 6, l = threadIdx.x & 63, half = l >> 5, cl = l & 31;
  int bid = blockIdx.x;
  if (bid < 500) {
    gath128(xsb, rpd, csd, aggd, bid * 4 + wv, half, cl);
  } else {
    int n = (bid - 500) * 4 + wv;
    if (n >= N_S) return;
    int b = rps[n], e = rps[n + 1];
    float a0 = 0.f, a1 = 0.f;
    int i = b + half;
    for (; i + 2 < e; i += 4) {
      unsigned v0 = *(const unsigned*)(xdb + (long long)css[i] * 64 + cl * 2);
      unsigned v1 = *(const unsigned*)(xdb + (long long)css[i + 2] * 64 + cl * 2);
      a0 += bf2f((unsigned short)(v0 & 0xffff)) + bf2f((unsigned short)(v1 & 0xffff));
      a1 += bf2f((unsigned short)(v0 >> 16))    + bf2f((unsigned short)(v1 >> 16));
    }
    for (; i < e; i += 2) {
      unsigned v0 = *(const unsigned*)(xdb + (long long)css[i] * 64 + cl * 2);
      a0 += bf2f((unsigned short)(v0 & 0xffff));
      a1 += bf2f((unsigned short)(v0 >> 16));
    }
    a0 += __shfl_xor(a0, 32); a1 += __shfl_xor(a1, 32);
    if (!half) {
      ushort2 o = {f2bf(a0), f2bf(a1)};
      *(ushort2*)&aggs[(long long)n * 64 + cl * 2] = o;
    }
  }
}

__global__ __launch_bounds__(256) void k_gather3(
    const unsigned short* __restrict__ xs2b, const unsigned short* __restrict__ xd2b,
    const int* __restrict__ rpd, const int* __restrict__ csd,
    const int* __restrict__ rps, const int* __restrict__ css,
    unsigned short* __restrict__ aggd, unsigned short* __restrict__ aggs) {
  int wv = threadIdx.x >> 6, l = threadIdx.x & 63, half = l >> 5, cl = l & 31;
  int bid = blockIdx.x;
  if (bid < 500) {
    gath128(xs2b, rpd, csd, aggd, bid * 4 + wv, half, cl);
  } else {
    int n = (bid - 500) * 4 + wv;
    if (n >= N_S) return;
    gath128(xd2b, rps, css, aggs, n, half, cl);
  }
}

// ================= generic fused MFMA GEMM =================
struct GD {
  const unsigned short *A0, *P0, *A1, *P1;
  const float* bias;
  void* out;
  int K0, K1, N, M, relu, outmode, y0;   // outmode: 0=f32 1=bf16 2=f16
};
template<int ND> struct GDs { GD d[ND]; };

template<int ND>
__global__ __launch_bounds__(256) void k_mfma(GDs<ND> g) {
  int by = blockIdx.y;
  int di = 0;
  #pragma unroll
  for (int i = 1; i < ND; ++i) if (by >= g.d[i].y0) di = i;
  GD d = g.d[di];
  int ytile = by - d.y0;
  int c0 = blockIdx.x * 64;
  if (c0 >= d.M) return;
  int w = threadIdx.x >> 6, l = threadIdx.x & 63;
  int r0 = ytile * 64 + w * 16;
  if (r0 >= d.N) return;
  int lg = l >> 4, lo = l & 15;
  f32x4 acc[4] = {};
  int arow = r0 + lo; arow = (arow < d.N) ? arow : (d.N - 1);
  int mt = d.M >> 4;
  int ct0 = c0 >> 4;
  const unsigned short* a0 = d.A0 + (long long)arow * d.K0 + lg * 8;
  for (int kt = 0; kt < (d.K0 >> 5); ++kt) {
    short8 a = *(const short8*)(a0 + kt * 32);
    #pragma unroll
    for (int ct = 0; ct < 4; ++ct) {
      short8 b = *(const short8*)(d.P0 + ((long long)(kt * mt + ct0 + ct) * 64 + l) * 8);
      acc[ct] = __builtin_amdgcn_mfma_f32_16x16x32_bf16(a, b, acc[ct], 0, 0, 0);
    }
  }
  if (d.K1) {
    const unsigned short* a1 = d.A1 + (long long)arow * d.K1 + lg * 8;
    for (int kt = 0; kt < (d.K1 >> 5); ++kt) {
      short8 a = *(const short8*)(a1 + kt * 32);
      #pragma unroll
      for (int ct = 0; ct < 4; ++ct) {
        short8 b = *(const short8*)(d.P1 + ((long long)(kt * mt + ct0 + ct) * 64 + l) * 8);
        acc[ct] = __builtin_amdgcn_mfma_f32_16x16x32_bf16(a, b, acc[ct], 0, 0, 0);
      }
    }
  }
  #pragma unroll
  for (int ct = 0; ct < 4; ++ct) {
    int col = c0 + ct * 16 + lo;
    float bv = d.bias[col];
    #pragma unroll
    for (int r = 0; r < 4; ++r) {
      int grow = r0 + lg * 4 + r;
      if (grow < d.N) {
        float v = acc[ct][r] + bv;
        if (d.relu) v = fmaxf(v, 0.f);
        if (d.outmode == 1)
          ((unsigned short*)d.out)[(long long)grow * d.M + col] = f2bf(v);
        else if (d.outmode == 2)
          ((unsigned short*)d.out)[(long long)grow * d.M + col] = f2h(v);
        else
          ((float*)d.out)[(long long)grow * d.M + col] = v;
      }
    }
  }
}

// ================= GATv2 node body: packed-f16 math, 2-deep pipeline ===========
// acc2 stores exp(sc-m)*x/256 in f16; overflow-safe with defer-threshold 4.
template<int WPN>
__device__ __forceinline__ void gat_node(
    const unsigned short* __restrict__ xl, const unsigned short* __restrict__ xr,
    const int* __restrict__ rowptr, const int* __restrict__ srcid,
    const unsigned short* __restrict__ att16, const float* __restrict__ bias,
    unsigned short* __restrict__ outb, int node, int wsub, int l,
    float (*lm)[8], float (*lss)[8], unsigned (*lacc)[8][64]) {
  int h = l >> 3, sub = l & 7;
  int cbase = h * 128 + sub * 16;
  U8h xr8, at8;
  { const uint4* p = (const uint4*)(xr + (long long)node * 1024 + cbase);
    xr8.u[0] = p[0]; xr8.u[1] = p[1]; }
  { const uint4* p = (const uint4*)(att16 + cbase);
    at8.u[0] = p[0]; at8.u[1] = p[1]; }
  const h2 neg2 = {(_Float16)NEG, (_Float16)NEG};
  float m = -INFINITY, s = 0.f;
  h2 acc2[8] = {};
  int b = rowptr[node], e = rowptr[node + 1];

  auto process = [&](U8h& x) {
    float sc = 0.f;
    #pragma unroll
    for (int j = 0; j < 8; ++j) {
      h2 t = x.h[j] + xr8.h[j];
      h2 lk = __builtin_elementwise_max(t, t * neg2);
      sc = __builtin_amdgcn_fdot2(lk, at8.h[j], sc, false);
    }
    sc += __shfl_xor(sc, 1); sc += __shfl_xor(sc, 2); sc += __shfl_xor(sc, 4);
    if (sc > m + 4.f) {                          // defer-rescale (T13, thr=4)
      float scl = __expf(m - sc);
      _Float16 sh = (_Float16)scl;
      h2 s2 = {sh, sh};
      #pragma unroll
      for (int j = 0; j < 8; ++j) acc2[j] *= s2;
      s *= scl; m = sc;
    }
    float a = __expf(sc - m);
    s += a;
    _Float16 ah = (_Float16)(a * 0.00390625f);   // /256 pre-scale vs f16 overflow
    h2 a2 = {ah, ah};
    #pragma unroll
    for (int j = 0; j < 8; ++j) acc2[j] = __builtin_elementwise_fma(a2, x.h[j], acc2[j]);
  };

  int i = b + wsub;
  U8h c, d;
  bool hc = (i < e), hd = (i + WPN < e);
  if (hc) { const uint4* p = (const uint4*)(xl + (long long)srcid[i] * 1024 + cbase); c.u[0] = p[0]; c.u[1] = p[1]; }
  if (hd) { const uint4* p = (const uint4*)(xl + (long long)srcid[i + WPN] * 1024 + cbase); d.u[0] = p[0]; d.u[1] = p[1]; }
  while (hc) {
    int inx = i + 2 * WPN;
    U8h n0, n1;
    bool h0 = (inx < e), h1 = (inx + WPN < e);
    if (h0) { const uint4* p = (const uint4*)(xl + (long long)srcid[inx] * 1024 + cbase); n0.u[0] = p[0]; n0.u[1] = p[1]; }
    if (h1) { const uint4* p = (const uint4*)(xl + (long long)srcid[inx + WPN] * 1024 + cbase); n1.u[0] = p[0]; n1.u[1] = p[1]; }
    process(c);
    if (hd) process(d);
    c = n0; d = n1; hc = h0; hd = h1; i = inx;
  }

  float val[16];
  if constexpr (WPN == 4) {
    if (sub == 0) { lm[wsub][h] = m; lss[wsub][h] = s; }
    U8h tmp;
    #pragma unroll
    for (int j = 0; j < 8; ++j) tmp.h[j] = acc2[j];
    #pragma unroll
    for (int j = 0; j < 8; ++j) lacc[wsub][j][l] = tmp.w[j];   // transposed: conflict-free
    __syncthreads();
    if (wsub != 0) return;
    float M2 = fmaxf(fmaxf(lm[0][h], lm[1][h]), fmaxf(lm[2][h], lm[3][h]));
    float S = 0.f;
    #pragma unroll
    for (int j = 0; j < 16; ++j) val[j] = 0.f;
    #pragma unroll
    for (int w2 = 0; w2 < 4; ++w2) {
      float scw = (M2 == -INFINITY) ? 0.f : __expf(lm[w2][h] - M2);
      S = fmaf(scw, lss[w2][h], S);
      #pragma unroll
      for (int j = 0; j < 8; ++j) {
        unsigned uw = lacc[w2][j][l];
        h2 hv; __builtin_memcpy(&hv, &uw, 4);
        val[2 * j]     = fmaf(scw, (float)hv[0], val[2 * j]);
        val[2 * j + 1] = fmaf(scw, (float)hv[1], val[2 * j + 1]);
      }
    }
    float inv = (S > 0.f) ? 256.f / S : 0.f;
    #pragma unroll
    for (int j = 0; j < 16; ++j) val[j] *= inv;
  } else {
    float inv = (s > 0.f) ? 256.f / s : 0.f;
    #pragma unroll
    for (int j = 0; j < 8; ++j) {
      val[2 * j]     = (float)acc2[j][0] * inv;
      val[2 * j + 1] = (float)acc2[j][1] * inv;
    }
  }
  #pragma unroll
  for (int j = 0; j < 16; ++j) {
    val[j] += __shfl_xor(val[j], 8);
    val[j] += __shfl_xor(val[j], 16);
    val[j] += __shfl_xor(val[j], 32);
  }
  if (l < 8) {
    #pragma unroll
    for (int q = 0; q < 4; ++q) {
      float4 bq = *(const float4*)&bias[sub * 16 + q * 4];
      ushort4 o;
      o.x = f2bf(fmaxf(val[q * 4 + 0] * 0.125f + bq.x, 0.f));
      o.y = f2bf(fmaxf(val[q * 4 + 1] * 0.125f + bq.y, 0.f));
      o.z = f2bf(fmaxf(val[q * 4 + 2] * 0.125f + bq.z, 0.f));
      o.w = f2bf(fmaxf(val[q * 4 + 3] * 0.125f + bq.w, 0.f));
      *(ushort4*)&outb[(long long)node * 128 + sub * 16 + q * 4] = o;
    }
  }
}

__global__ __launch_bounds__(256) void k_gat_both(
    const unsigned short* __restrict__ XLsd, const unsigned short* __restrict__ XRsd,
    const int* __restrict__ rpd, const int* __restrict__ csd,
    const unsigned short* __restrict__ att_sd, const float* __restrict__ bias_sd,
    unsigned short* __restrict__ XD2b,
    const unsigned short* __restrict__ XLds, const unsigned short* __restrict__ XRds,
    const int* __restrict__ rps, const int* __restrict__ css,
    const unsigned short* __restrict__ att_ds, const float* __restrict__ bias_ds,
    unsigned short* __restrict__ XS2b) {
  __shared__ float lm[4][8], lss[4][8];
  __shared__ unsigned lacc[4][8][64];
  int widx = threadIdx.x >> 6, l = threadIdx.x & 63;
  if (blockIdx.x < (unsigned)N_D) {
    gat_node<4>(XLsd, XRsd, rpd, csd, att_sd, bias_sd, XD2b,
                blockIdx.x, widx, l, lm, lss, lacc);
  } else {
    int node = (blockIdx.x - N_D) * 4 + widx;
    if (node < N_S)
      gat_node<1>(XLds, XRds, rps, css, att_ds, bias_ds, XS2b,
                  node, 0, l, lm, lss, lacc);
  }
}

// ================= classifier: 4 edges/wave, float4 loads =================
__global__ void k_dot64(const float* __restrict__ xs, const float* __restrict__ xd,
                        const int* __restrict__ ls, const int* __restrict__ ld,
                        float* __restrict__ out, int L) {
  long long t = (long long)blockIdx.x * blockDim.x + threadIdx.x;
  int wave = (int)(t >> 6), lane = (int)(t & 63);
  int q = lane >> 4, sub = lane & 15;
  int eidx = wave * 4 + q;
  if (eidx >= L) return;
  const float4* a = (const float4*)(xs + (long long)ls[eidx] * 64);
  const float4* b = (const float4*)(xd + (long long)ld[eidx] * 64);
  float4 va = a[sub], vb = b[sub];
  float v = va.x * vb.x + va.y * vb.y + va.z * vb.z + va.w * vb.w;
  v += __shfl_xor(v, 1); v += __shfl_xor(v, 2);
  v += __shfl_xor(v, 4); v += __shfl_xor(v, 8);
  if (sub == 0) out[eidx] = v;
}

extern "C" void kernel_launch(void* const* d_in, const int* in_sizes, int n_in,
                              void* d_out, int out_size, void* d_ws, size_t ws_size,
                              hipStream_t stream) {
  const float* x_s = (const float*)d_in[0];
  const float* x_d = (const float*)d_in[1];
  const int* esrc = (const int*)d_in[2];
  const int* edst = (const int*)d_in[3];
  const int* lsrc = (const int*)d_in[4];
  const int* ldst = (const int*)d_in[5];
  const float* W1rel_sd  = (const float*)d_in[6];
  const float* b1_sd     = (const float*)d_in[7];
  const float* W1root_sd = (const float*)d_in[8];
  const float* W1rel_ds  = (const float*)d_in[9];
  const float* b1_ds     = (const float*)d_in[10];
  const float* W1root_ds = (const float*)d_in[11];
  const float *Wl2_sd = (const float*)d_in[12], *bl2_sd = (const float*)d_in[13],
              *Wr2_sd = (const float*)d_in[14], *br2_sd = (const float*)d_in[15],
              *att2_sd = (const float*)d_in[16], *bias2_sd = (const float*)d_in[17];
  const float *Wl2_ds = (const float*)d_in[18], *bl2_ds = (const float*)d_in[19],
              *Wr2_ds = (const float*)d_in[20], *br2_ds = (const float*)d_in[21],
              *att2_ds = (const float*)d_in[22], *bias2_ds = (const float*)d_in[23];
  const float *W3rel_sd = (const float*)d_in[24], *b3_sd = (const float*)d_in[25],
              *W3root_sd = (const float*)d_in[26];
  const float *W3rel_ds = (const float*)d_in[27], *b3_ds = (const float*)d_in[28],
              *W3root_ds = (const float*)d_in[29];
  float* out = (float*)d_out;

  // ---- workspace arena ----
  float* w = (float*)d_ws;
  long long off = 0;
  auto alloc = [&](long long n) { float* p = w + off; off += (n + 63) & ~63LL; return p; };
  unsigned short* xsb   = (unsigned short*)alloc((long long)N_S * 64);   // bf16 [N_S,128]
  unsigned short* xdb   = (unsigned short*)alloc((long long)N_D * 32);   // bf16 [N_D,64]
  unsigned short* AGGDb = (unsigned short*)alloc((long long)N_D * 64);
  unsigned short* AGGSb = (unsigned short*)alloc((long long)N_S * 32);
  unsigned short* XS1b  = (unsigned short*)alloc((long long)N_S * 64);   // bf16
  unsigned short* XD1b  = (unsigned short*)alloc((long long)N_D * 64);   // bf16
  unsigned short* XLsd  = (unsigned short*)alloc((long long)N_S * 512);  // f16 [N_S,1024]
  unsigned short* XRsd  = (unsigned short*)alloc((long long)N_D * 512);  // f16
  unsigned short* XLds  = (unsigned short*)alloc((long long)N_D * 512);  // f16
  unsigned short* XRds  = (unsigned short*)alloc((long long)N_S * 512);  // f16
  unsigned short* XS2b  = (unsigned short*)alloc((long long)N_S * 64);   // bf16
  unsigned short* XD2b  = (unsigned short*)alloc((long long)N_D * 64);   // bf16
  unsigned short* AGD3b = (unsigned short*)alloc((long long)N_D * 64);
  unsigned short* AGS3b = (unsigned short*)alloc((long long)N_S * 64);
  float* XS3 = alloc((long long)N_S * 64);
  float* XD3 = alloc((long long)N_D * 64);
  unsigned short* att16 = (unsigned short*)alloc(1024 + 64);             // f16 [2][1024]
  unsigned short* pk[12];
  const int pksz[12] = {128 * 128, 64 * 128, 64 * 128, 128 * 128,
                        131072, 131072, 131072, 131072,
                        128 * 64, 128 * 64, 128 * 64, 128 * 64};
  for (int i = 0; i < 12; ++i) pk[i] = (unsigned short*)alloc(pksz[i] / 2 + 64);
  int* rowptr_d = (int*)alloc(N_D + 64);
  int* rowptr_s = (int*)alloc(N_S + 64);
  int* cur_all  = (int*)alloc(N_D + N_S + 128);
  int* cur_d = cur_all;
  int* cur_s = cur_all + N_D + 64;
  int* csrc_d = (int*)alloc(E_N);
  int* csrc_s = (int*)alloc(E_N);
  (void)ws_size; (void)in_sizes; (void)n_in; (void)out_size;

  // ================= prep (hist + cvt + pack + att) =================
  hipMemsetAsync(cur_all, 0, (size_t)(N_D + N_S + 128) * 4, stream);
  PrepArgs pa = {esrc, edst, cur_s, cur_d, x_s, x_d, xsb, xdb, att2_sd, att2_ds, att16};
  Pk12 pkk = {{{W1rel_sd, pk[0], 128, 128}, {W1root_sd, pk[1], 64, 128},
               {W1rel_ds, pk[2], 64, 128},  {W1root_ds, pk[3], 128, 128},
               {Wl2_sd, pk[4], 128, 1024},  {Wr2_sd, pk[5], 128, 1024},
               {Wl2_ds, pk[6], 128, 1024},  {Wr2_ds, pk[7], 128, 1024},
               {W3rel_sd, pk[8], 128, 64},  {W3root_sd, pk[9], 128, 64},
               {W3rel_ds, pk[10], 128, 64}, {W3root_ds, pk[11], 128, 64}}};
  k_prep<<<2542, 256, 0, stream>>>(pa, pkk);
  k_scan2<<<2, 1024, 0, stream>>>(cur_d, rowptr_d, N_D, cur_s, rowptr_s, N_S);
  k_scat2<<<391, 256, 0, stream>>>(esrc, edst, cur_d, cur_s, csrc_d, csrc_s, E_N);

  // ================= layer 1 =================
  k_gather1<<<3000, 256, 0, stream>>>(xsb, xdb, rowptr_d, csrc_d, rowptr_s, csrc_s,
                                      AGGDb, AGGSb);
  {
    GDs<2> g = {{{AGGDb, pk[0], xdb, pk[1], b1_sd, XD1b, 128, 64, N_D, 128, 1, 1, 0},
                 {AGGSb, pk[2], xsb, pk[3], b1_ds, XS1b, 64, 128, N_S, 128, 1, 1, 32}}};
    k_mfma<2><<<dim3(2, 189), 256, 0, stream>>>(g);
  }

  // ================= layer 2 (projections f16-out, fused GAT) =================
  {
    GDs<4> g = {{{XS1b, pk[4], nullptr, nullptr, bl2_sd, XLsd, 128, 0, N_S, 1024, 0, 2, 0},
                 {XD1b, pk[5], nullptr, nullptr, br2_sd, XRsd, 128, 0, N_D, 1024, 0, 2, 157},
                 {XD1b, pk[6], nullptr, nullptr, bl2_ds, XLds, 128, 0, N_D, 1024, 0, 2, 189},
                 {XS1b, pk[7], nullptr, nullptr, br2_ds, XRds, 128, 0, N_S, 1024, 0, 2, 221}}};
    k_mfma<4><<<dim3(16, 378), 256, 0, stream>>>(g);
  }
  k_gat_both<<<N_D + (N_S + 3) / 4, 256, 0, stream>>>(
      XLsd, XRsd, rowptr_d, csrc_d, att16, bias2_sd, XD2b,
      XLds, XRds, rowptr_s, csrc_s, att16 + 1024, bias2_ds, XS2b);

  // ================= layer 3 =================
  k_gather3<<<3000, 256, 0, stream>>>(XS2b, XD2b, rowptr_d, csrc_d, rowptr_s, csrc_s,
                                      AGD3b, AGS3b);
  {
    GDs<2> g = {{{AGD3b, pk[8], XD2b, pk[9], b3_sd, XD3, 128, 128, N_D, 64, 0, 0, 0},
                 {AGS3b, pk[10], XS2b, pk[11], b3_ds, XS3, 128, 128, N_S, 64, 0, 0, 32}}};
    k_mfma<2><<<dim3(1, 189), 256, 0, stream>>>(g);
  }

  // ================= classifier =================
  k_dot64<<<(L_N * 16 + 255) / 256, 256, 0, stream>>>(XS3, XD3, lsrc, ldst, out, L_N);
}